// Round 7
// baseline (311.113 us; speedup 1.0000x reference)
//
#include <hip/hip_runtime.h>
#include <hip/hip_bf16.h>

typedef unsigned short u16;
typedef unsigned int u32;
typedef __attribute__((ext_vector_type(8))) short short8;
typedef __attribute__((ext_vector_type(4))) float f32x4;
typedef __attribute__((ext_vector_type(2))) float f32x2;

#define BCAP 8192   // fixed bucket capacity (avg fill ~4092 at E=1.6M, NB=391)
#define BSH  13

__device__ __forceinline__ float bf2f(u16 h) {
  return __uint_as_float(((u32)h) << 16);
}
__device__ __forceinline__ float ldconv(const void* p, int i, int fl) {
  return fl ? bf2f(((const u16*)p)[i]) : ((const float*)p)[i];
}
__device__ __forceinline__ u16 f2bf(float v) {
  __hip_bfloat16 h = __float2bfloat16(v);
  return *(u16*)&h;
}

// ------------------------- weight conversion + dtype sniff + counter zeroing
// wbh (u16): W1T [0,4096) W2T [4096,8192) fc1T [8192,24576)   (all [n][k], k=64)
// wbf (f32): b1[0,64) b2[64,128) fc1b[128,384) fc2w[384,640) fc2b[640]
__global__ __launch_bounds__(256) void k_conv_w(const void* x,
                         const void* W1, const void* b1, const void* W2, const void* b2,
                         const void* f1w, const void* f1b, const void* f2w, const void* f2b,
                         u16* wbh, float* wbf, int* flag, float* ssum, int* bcnt) {
  __shared__ float red[256];
  int t = threadIdx.x;
  // each block sniffs dtype independently (reads 2 KB of x, L2-resident)
  const u16* hx = (const u16*)x;
  float m = 0.f;
  for (int i = t; i < 1024; i += 256) m = fmaxf(m, fabsf(bf2f(hx[i])));
  red[t] = m; __syncthreads();
  for (int off = 128; off > 0; off >>= 1) {
    if (t < off) red[t] = fmaxf(red[t], red[t + off]);
    __syncthreads();
  }
  int fl = (red[0] < 1000.0f) ? 1 : 0;
  if (blockIdx.x == 0) {
    bcnt[t] = 0; bcnt[t + 256] = 0;
    if (t == 0) { *flag = fl; *ssum = 0.f; }
  }
  int i = blockIdx.x * 256 + t;
  if (i < 4096) {
    int n = i >> 6, k = i & 63;
    wbh[i] = f2bf(ldconv(W1, k * 64 + n, fl));
  } else if (i < 8192) {
    int j = i - 4096; int n = j >> 6, k = j & 63;
    wbh[i] = f2bf(ldconv(W2, k * 64 + n, fl));
  } else if (i < 24576) {
    int j = i - 8192; int n = j >> 6, k = j & 63;
    wbh[i] = f2bf(ldconv(f1w, k * 256 + n, fl));
  } else if (i < 24576 + 641) {
    int j = i - 24576;
    float v;
    if (j < 64)       v = ldconv(b1,  j,       fl);
    else if (j < 128) v = ldconv(b2,  j - 64,  fl);
    else if (j < 384) v = ldconv(f1b, j - 128, fl);
    else if (j < 640) v = ldconv(f2w, j - 384, fl);
    else              v = ldconv(f2b, 0,       fl);
    wbf[j] = v;
  }
}

// ---------------- bucketed edge sort, single pass (fixed-capacity buckets)
__global__ __launch_bounds__(256) void k_bfill(const int* __restrict__ eidx, int E,
                                               int* bcnt, u32* bdata) {
  __shared__ int hist[512];
  __shared__ int base[512];
  int t = threadIdx.x;
  hist[t] = 0; hist[t + 256] = 0;
  __syncthreads();
  int e0 = blockIdx.x * 8192;
  int e1 = min(e0 + 8192, E);
  for (int e = e0 + t; e < e1; e += 256) atomicAdd(&hist[eidx[E + e] >> 8], 1);
  __syncthreads();
  for (int j = t; j < 512; j += 256) {
    int c = hist[j];
    base[j] = c ? atomicAdd(&bcnt[j], c) : 0;
    hist[j] = 0;
  }
  __syncthreads();
  for (int e = e0 + t; e < e1; e += 256) {
    int src = eidx[e];
    int tgt = eidx[E + e];
    int b = tgt >> 8;
    int idx = base[b] + atomicAdd(&hist[b], 1);
    if (idx < BCAP) bdata[((size_t)b << BSH) + idx] = ((u32)src << 8) | (u32)(tgt & 255);
  }
}

// One block per bucket: histogram -> deg/dinv/ptr, LDS scan, LDS scatter, seq write.
// ptr is bucket-strided (base = b*BCAP) -- consumers use ptr/deg only.
__global__ __launch_bounds__(256) void k_csr(const u32* __restrict__ bdata,
                                             const int* __restrict__ bcnt,
                                             int* __restrict__ deg, float* __restrict__ dinv,
                                             int* __restrict__ ptr, int* __restrict__ crow,
                                             int N) {
  __shared__ int lds[BCAP];
  __shared__ int hist[256];
  __shared__ int tmp[256];
  __shared__ int cur[256];
  int b = blockIdx.x, t = threadIdx.x;
  int node0 = b << 8;
  int ncnt = min(256, N - node0);
  size_t base = (size_t)b << BSH;
  int cnt = min(bcnt[b], BCAP);
  hist[t] = 0;
  __syncthreads();
  for (int e = t; e < cnt; e += 256) atomicAdd(&hist[bdata[base + e] & 255], 1);
  __syncthreads();
  int h = hist[t];
  if (t < ncnt) {
    deg[node0 + t] = h + 1;
    dinv[node0 + t] = 1.0f / sqrtf((float)(h + 1));
  }
  tmp[t] = h; __syncthreads();
  for (int off = 1; off < 256; off <<= 1) {
    int u = (t >= off) ? tmp[t - off] : 0;
    __syncthreads();
    tmp[t] += u;
    __syncthreads();
  }
  int excl = tmp[t] - h;
  if (t < ncnt) ptr[node0 + t] = (int)base + excl;
  cur[t] = excl;
  __syncthreads();
  for (int e = t; e < cnt; e += 256) {
    u32 pk = bdata[base + e];
    int pos = atomicAdd(&cur[pk & 255], 1);
    if (pos < BCAP) lds[pos] = (int)(pk >> 8);
  }
  __syncthreads();
  for (int j = t; j < cnt; j += 256) crow[base + j] = lds[j];
}

// ---------------- transform: out[r,:] = dinv[r] * (in[r,:] @ W)  (MFMA, bf16)
__global__ __launch_bounds__(256) void k_xform(const void* __restrict__ in,
                                               const int* __restrict__ flagp,
                                               const u16* __restrict__ wT,
                                               const float* __restrict__ dinv,
                                               u16* __restrict__ out, int N) {
  __shared__ __align__(16) u16 ws[64 * 72];
  int t = threadIdx.x;
  #pragma unroll
  for (int f = t; f < 512; f += 256) {
    int n = f >> 3, o = f & 7;
    *(float4*)&ws[n * 72 + o * 8] = ((const float4*)wT)[f];
  }
  __syncthreads();
  int fl = *flagp;
  int lane = t & 63, wid = t >> 6;
  int g = lane >> 4, c = lane & 15;
  int arow = blockIdx.x * 64 + wid * 16 + c;
  short8 a0 = {0, 0, 0, 0, 0, 0, 0, 0}, a1 = {0, 0, 0, 0, 0, 0, 0, 0};
  if (arow < N) {
    if (fl) {
      const u16* p = (const u16*)in + (size_t)arow * 64 + g * 8;
      a0 = *(const short8*)p;
      a1 = *(const short8*)(p + 32);
    } else {
      const float* p = (const float*)in + (size_t)arow * 64 + g * 8;
      u16 tmpv[16];
      #pragma unroll
      for (int j = 0; j < 8; j++) tmpv[j] = f2bf(p[j]);
      #pragma unroll
      for (int j = 0; j < 8; j++) tmpv[8 + j] = f2bf(p[32 + j]);
      a0 = *(short8*)tmpv;
      a1 = *(short8*)(tmpv + 8);
    }
  }
  int rbase = blockIdx.x * 64 + wid * 16 + g * 4;
  float dv[4];
  #pragma unroll
  for (int r = 0; r < 4; r++) dv[r] = (rbase + r < N) ? dinv[rbase + r] : 0.f;
  #pragma unroll
  for (int tile = 0; tile < 4; tile++) {
    short8 b0 = *(const short8*)&ws[(tile * 16 + c) * 72 + g * 8];
    short8 b1 = *(const short8*)&ws[(tile * 16 + c) * 72 + g * 8 + 32];
    f32x4 z = {0.f, 0.f, 0.f, 0.f};
    f32x4 acc = __builtin_amdgcn_mfma_f32_16x16x32_bf16(a0, b0, z, 0, 0, 0);
    acc = __builtin_amdgcn_mfma_f32_16x16x32_bf16(a1, b1, acc, 0, 0, 0);
    #pragma unroll
    for (int r = 0; r < 4; r++) {
      int orow = rbase + r;
      if (orow < N) out[(size_t)orow * 64 + tile * 16 + c] = f2bf(acc[r] * dv[r]);
    }
  }
}

// --------- shared agg-phase helper: wave aggregates 16 nodes into LDS rows
// rows stride 72 u16. Produces relu(dinv[i]*sum + bias) in bf16.
__device__ __forceinline__ void agg_rows(const u16* __restrict__ src,
                                         const int* __restrict__ crow,
                                         const int* __restrict__ ptr,
                                         const int* __restrict__ deg,
                                         const float* __restrict__ dinv,
                                         const float* __restrict__ bias,
                                         u16* rows, int node0w, int wid, int lane, int N) {
  int sub = lane >> 3;
  int fo  = lane & 7;
  const u16* gbase = src + (size_t)fo * 8;
  for (int n = 0; n < 16; n++) {
    int i = node0w + n;
    f32x2 p0 = {0.f, 0.f}, p1 = {0.f, 0.f}, p2 = {0.f, 0.f}, p3 = {0.f, 0.f};
    if (i < N) {
      int start = ptr[i];
      int total = deg[i];
      #pragma unroll 4
      for (int e = sub; e < total; e += 8) {
        int r = (e == 0) ? i : crow[start + e - 1];
        uint4 v = *(const uint4*)(gbase + (size_t)r * 64);
        p0 += (f32x2){__uint_as_float(v.x << 16), __uint_as_float(v.x & 0xffff0000u)};
        p1 += (f32x2){__uint_as_float(v.y << 16), __uint_as_float(v.y & 0xffff0000u)};
        p2 += (f32x2){__uint_as_float(v.z << 16), __uint_as_float(v.z & 0xffff0000u)};
        p3 += (f32x2){__uint_as_float(v.w << 16), __uint_as_float(v.w & 0xffff0000u)};
      }
    }
    float a0 = p0.x, a1 = p0.y, a2 = p1.x, a3 = p1.y;
    float a4 = p2.x, a5 = p2.y, a6 = p3.x, a7 = p3.y;
    #pragma unroll
    for (int off = 8; off < 64; off <<= 1) {
      a0 += __shfl_xor(a0, off); a1 += __shfl_xor(a1, off);
      a2 += __shfl_xor(a2, off); a3 += __shfl_xor(a3, off);
      a4 += __shfl_xor(a4, off); a5 += __shfl_xor(a5, off);
      a6 += __shfl_xor(a6, off); a7 += __shfl_xor(a7, off);
    }
    if (sub == 0) {
      u16 o[8] = {0, 0, 0, 0, 0, 0, 0, 0};
      if (i < N) {
        float di = dinv[i];
        float4 b0 = ((const float4*)bias)[2 * fo];
        float4 b1 = ((const float4*)bias)[2 * fo + 1];
        o[0] = f2bf(fmaxf(fmaf(a0, di, b0.x), 0.f));
        o[1] = f2bf(fmaxf(fmaf(a1, di, b0.y), 0.f));
        o[2] = f2bf(fmaxf(fmaf(a2, di, b0.z), 0.f));
        o[3] = f2bf(fmaxf(fmaf(a3, di, b0.w), 0.f));
        o[4] = f2bf(fmaxf(fmaf(a4, di, b1.x), 0.f));
        o[5] = f2bf(fmaxf(fmaf(a5, di, b1.y), 0.f));
        o[6] = f2bf(fmaxf(fmaf(a6, di, b1.z), 0.f));
        o[7] = f2bf(fmaxf(fmaf(a7, di, b1.w), 0.f));
      }
      *(uint4*)&rows[(wid * 16 + n) * 72 + fo * 8] = *(uint4*)o;
    }
  }
}

// ---------------- fused: aggregate(conv1 out) -> xform with W2 -> dinv-scale -> dst
__global__ __launch_bounds__(256) void k_aggx(const u16* __restrict__ src, u16* __restrict__ dst,
                                              const int* __restrict__ crow,
                                              const int* __restrict__ ptr,
                                              const int* __restrict__ deg,
                                              const float* __restrict__ dinv,
                                              const float* __restrict__ bias,
                                              const u16* __restrict__ wT, int N) {
  __shared__ __align__(16) u16 wsW[64 * 72];
  __shared__ __align__(16) u16 rows[64 * 72];
  int t = threadIdx.x;
  #pragma unroll
  for (int f = t; f < 512; f += 256) {
    int n = f >> 3, o = f & 7;
    *(float4*)&wsW[n * 72 + o * 8] = ((const float4*)wT)[f];
  }
  __syncthreads();
  int lane = t & 63, wid = t >> 6;
  int node0w = blockIdx.x * 64 + wid * 16;
  agg_rows(src, crow, ptr, deg, dinv, bias, rows, node0w, wid, lane, N);
  // wave reads only its own rows -> no barrier needed
  int g = lane >> 4, c = lane & 15;
  short8 a0 = *(const short8*)&rows[(wid * 16 + c) * 72 + g * 8];
  short8 a1 = *(const short8*)&rows[(wid * 16 + c) * 72 + g * 8 + 32];
  int rbase = node0w + g * 4;
  float dv[4];
  #pragma unroll
  for (int r = 0; r < 4; r++) dv[r] = (rbase + r < N) ? dinv[rbase + r] : 0.f;
  #pragma unroll
  for (int tile = 0; tile < 4; tile++) {
    short8 b0 = *(const short8*)&wsW[(tile * 16 + c) * 72 + g * 8];
    short8 b1 = *(const short8*)&wsW[(tile * 16 + c) * 72 + g * 8 + 32];
    f32x4 z = {0.f, 0.f, 0.f, 0.f};
    f32x4 acc = __builtin_amdgcn_mfma_f32_16x16x32_bf16(a0, b0, z, 0, 0, 0);
    acc = __builtin_amdgcn_mfma_f32_16x16x32_bf16(a1, b1, acc, 0, 0, 0);
    #pragma unroll
    for (int r = 0; r < 4; r++) {
      int orow = rbase + r;
      if (orow < N) dst[(size_t)orow * 64 + tile * 16 + c] = f2bf(acc[r] * dv[r]);
    }
  }
}

// ---------------- fused: aggregate(conv2 out) -> fc1(relu) -> fc2 -> out + ssq
// fc1 staged in 2 phases of 128 cols; phase buffer overlays the rows buffer.
__global__ __launch_bounds__(256) void k_aggfc(const u16* __restrict__ src,
                                               const int* __restrict__ crow,
                                               const int* __restrict__ ptr,
                                               const int* __restrict__ deg,
                                               const float* __restrict__ dinv,
                                               const float* __restrict__ bias,
                                               const u16* __restrict__ fc1T,
                                               const float* __restrict__ wf,
                                               float* __restrict__ outf,
                                               float* __restrict__ ssum, int N) {
  __shared__ __align__(16) u16 wsF[128 * 72];  // rows occupy first 64*72 during agg
  __shared__ float red[16];
  int t = threadIdx.x;
  int lane = t & 63, wid = t >> 6;
  int node0w = blockIdx.x * 64 + wid * 16;
  agg_rows(src, crow, ptr, deg, dinv, bias, wsF, node0w, wid, lane, N);
  // pull A-frags into registers before wsF is overwritten by fc1 staging
  int g = lane >> 4, c = lane & 15;
  short8 a0 = *(const short8*)&wsF[(wid * 16 + c) * 72 + g * 8];
  short8 a1 = *(const short8*)&wsF[(wid * 16 + c) * 72 + g * 8 + 32];
  float psum[4] = {0.f, 0.f, 0.f, 0.f};
  for (int ph = 0; ph < 2; ph++) {
    __syncthreads();
    #pragma unroll
    for (int f = t; f < 1024; f += 256) {
      int n = f >> 3, o = f & 7;
      *(float4*)&wsF[n * 72 + o * 8] = ((const float4*)(fc1T + ph * 8192))[f];
    }
    __syncthreads();
    #pragma unroll
    for (int tile = 0; tile < 8; tile++) {
      short8 b0 = *(const short8*)&wsF[(tile * 16 + c) * 72 + g * 8];
      short8 b1 = *(const short8*)&wsF[(tile * 16 + c) * 72 + g * 8 + 32];
      f32x4 z = {0.f, 0.f, 0.f, 0.f};
      f32x4 acc = __builtin_amdgcn_mfma_f32_16x16x32_bf16(a0, b0, z, 0, 0, 0);
      acc = __builtin_amdgcn_mfma_f32_16x16x32_bf16(a1, b1, acc, 0, 0, 0);
      int col = ph * 128 + tile * 16 + c;
      float fb = wf[128 + col];
      float fw = wf[384 + col];
      #pragma unroll
      for (int r = 0; r < 4; r++) psum[r] += fmaxf(acc[r] + fb, 0.f) * fw;
    }
  }
  #pragma unroll
  for (int off = 1; off < 16; off <<= 1) {
    #pragma unroll
    for (int r = 0; r < 4; r++) psum[r] += __shfl_xor(psum[r], off);
  }
  float fc2b = wf[640];
  if (c == 0) {
    float ss = 0.f;
    int rbase = node0w + g * 4;
    #pragma unroll
    for (int r = 0; r < 4; r++) {
      int row = rbase + r;
      if (row < N) {
        float o = psum[r] + fc2b;
        outf[row] = o;
        ss += o * o;
      }
    }
    red[wid * 4 + g] = ss;
  }
  __syncthreads();
  if (t == 0) {
    float s = 0.f;
    #pragma unroll
    for (int j = 0; j < 16; j++) s += red[j];
    atomicAdd(ssum, s);
  }
}

// ------------------------------------------------------------- L2 norm write
__global__ void k_norm(const float* __restrict__ outf, const float* __restrict__ ssum,
                       void* dout, int N, const int* flag) {
  int i = blockIdx.x * blockDim.x + threadIdx.x;
  if (i >= N) return;
  float denom = fmaxf(sqrtf(*ssum), 1e-12f);
  float v = outf[i] / denom;
  if (*flag) ((__hip_bfloat16*)dout)[i] = __float2bfloat16(v);
  else       ((float*)dout)[i] = v;
}

extern "C" void kernel_launch(void* const* d_in, const int* in_sizes, int n_in,
                              void* d_out, int out_size, void* d_ws, size_t ws_size,
                              hipStream_t stream) {
  const void* x   = d_in[0];
  const int* eidx = (const int*)d_in[1];
  const void* W1  = d_in[2]; const void* b1  = d_in[3];
  const void* W2  = d_in[4]; const void* b2  = d_in[5];
  const void* f1w = d_in[6]; const void* f1b = d_in[7];
  const void* f2w = d_in[8]; const void* f2b = d_in[9];
  int N = in_sizes[0] / 64;
  int E = in_sizes[1] / 2;
  int NB = (N + 255) >> 8;           // 256-node buckets
  int GEB = (E + 8191) / 8192;

  char* ws = (char*)d_ws;
  size_t off = 0;
  auto alloc = [&](size_t b) {
    void* p = ws + off;
    off = (off + b + 255) & ~(size_t)255;
    return p;
  };
  int*   flag  = (int*)  alloc(4);
  float* ssum  = (float*)alloc(4);
  int*   bcnt  = (int*)  alloc(512 * 4);
  u32*   bdata = (u32*)  alloc((size_t)NB * BCAP * 4);
  int*   deg   = (int*)  alloc((size_t)N * 4);
  int*   ptr   = (int*)  alloc((size_t)N * 4);
  float* dinv  = (float*)alloc((size_t)N * 4);
  int*   crow  = (int*)  alloc((size_t)NB * BCAP * 4);
  u16*   wbh   = (u16*)  alloc(24576 * 2);
  float* wbf   = (float*)alloc(641 * 4);
  u16*   HT    = (u16*)  alloc((size_t)N * 64 * 2);
  u16*   HA    = (u16*)  alloc((size_t)N * 64 * 2);
  float* outf  = (float*)alloc((size_t)N * 4);

  int GN = (N + 255) / 256;
  int NT = (N + 63) / 64;

  k_conv_w<<<(24576 + 641 + 255) / 256, 256, 0, stream>>>(x, W1, b1, W2, b2, f1w, f1b, f2w, f2b,
                                                          wbh, wbf, flag, ssum, bcnt);
  k_bfill<<<GEB, 256, 0, stream>>>(eidx, E, bcnt, bdata);
  k_csr<<<NB, 256, 0, stream>>>(bdata, bcnt, deg, dinv, ptr, crow, N);

  // conv1 transform (reads raw x, converts inline)
  k_xform<<<NT, 256, 0, stream>>>(x, flag, wbh + 0, dinv, HT, N);
  // conv1 aggregate + conv2 transform (fused)
  k_aggx<<<NT, 256, 0, stream>>>(HT, HA, crow, ptr, deg, dinv, wbf + 0, wbh + 4096, N);
  // conv2 aggregate + MLP (fused)
  k_aggfc<<<NT, 256, 0, stream>>>(HA, crow, ptr, deg, dinv, wbf + 64, wbh + 8192, wbf,
                                  outf, ssum, N);
  // normalize + write
  k_norm<<<GN, 256, 0, stream>>>(outf, ssum, d_out, N, flag);
}

// Round 9
// 291.325 us; speedup vs baseline: 1.0679x; 1.0679x over previous
//
#include <hip/hip_runtime.h>
#include <hip/hip_bf16.h>

typedef unsigned short u16;
typedef unsigned int u32;
typedef __attribute__((ext_vector_type(8))) short short8;
typedef __attribute__((ext_vector_type(4))) float f32x4;

__device__ __forceinline__ float bf2f(u16 h) {
  return __uint_as_float(((u32)h) << 16);
}
__device__ __forceinline__ float ldconv(const void* p, int i, int fl) {
  return fl ? bf2f(((const u16*)p)[i]) : ((const float*)p)[i];
}
__device__ __forceinline__ u16 f2bf(float v) {
  __hip_bfloat16 h = __float2bfloat16(v);
  return *(u16*)&h;
}

// ---------------------------------------------------------------- dtype sniff
__global__ void k_flag(const void* x, int* flag, float* ssum, int* bcnt) {
  __shared__ float red[256];
  int t = threadIdx.x;
  const u16* h = (const u16*)x;
  float m = 0.f;
  for (int i = t; i < 1024; i += 256) m = fmaxf(m, fabsf(bf2f(h[i])));
  red[t] = m; __syncthreads();
  for (int off = 128; off > 0; off >>= 1) {
    if (t < off) red[t] = fmaxf(red[t], red[t + off]);
    __syncthreads();
  }
  bcnt[t] = 0; bcnt[t + 256] = 0;
  if (t == 0) { *flag = (red[0] < 1000.0f) ? 1 : 0; *ssum = 0.f; }
}

// ------------------------------------------------------- weight conversion
// wbh (u16): W1T [0,4096) W2T [4096,8192) fc1T [8192,24576)   (all [n][k], k=64)
// wbf (f32): b1[0,64) b2[64,128) fc1b[128,384) fc2w[384,640) fc2b[640]
__global__ void k_conv_w(const void* W1, const void* b1, const void* W2, const void* b2,
                         const void* f1w, const void* f1b, const void* f2w, const void* f2b,
                         u16* wbh, float* wbf, const int* flag) {
  int fl = *flag;
  int i = blockIdx.x * blockDim.x + threadIdx.x;
  if (i < 4096) {
    int n = i >> 6, k = i & 63;
    wbh[i] = f2bf(ldconv(W1, k * 64 + n, fl));
  } else if (i < 8192) {
    int j = i - 4096; int n = j >> 6, k = j & 63;
    wbh[i] = f2bf(ldconv(W2, k * 64 + n, fl));
  } else if (i < 24576) {
    int j = i - 8192; int n = j >> 6, k = j & 63;
    wbh[i] = f2bf(ldconv(f1w, k * 256 + n, fl));
  } else if (i < 24576 + 641) {
    int j = i - 24576;
    float v;
    if (j < 64)       v = ldconv(b1,  j,       fl);
    else if (j < 128) v = ldconv(b2,  j - 64,  fl);
    else if (j < 384) v = ldconv(f1b, j - 128, fl);
    else if (j < 640) v = ldconv(f2w, j - 384, fl);
    else              v = ldconv(f2b, 0,       fl);
    wbf[j] = v;
  }
}

// --------------------------------------- bucketed CSR build (256-node buckets)
__global__ __launch_bounds__(256) void k_bcount(const int* __restrict__ eidx, int E,
                                                int* bcnt, int* blockhist) {
  __shared__ int hist[512];
  int t = threadIdx.x;
  hist[t] = 0; hist[t + 256] = 0;
  __syncthreads();
  int e0 = blockIdx.x * 8192;
  int e1 = min(e0 + 8192, E);
  for (int e = e0 + t; e < e1; e += 256) atomicAdd(&hist[eidx[E + e] >> 8], 1);
  __syncthreads();
  int* bh = blockhist + blockIdx.x * 512;
  for (int j = t; j < 512; j += 256) {
    bh[j] = hist[j];
    if (hist[j]) atomicAdd(&bcnt[j], hist[j]);
  }
}

__global__ void k_bscan(const int* __restrict__ bcnt, int* bbase, int* bcur) {
  __shared__ int tmp[512];
  int t = threadIdx.x;
  int v = bcnt[t];
  tmp[t] = v; __syncthreads();
  for (int off = 1; off < 512; off <<= 1) {
    int u = (t >= off) ? tmp[t - off] : 0;
    __syncthreads();
    tmp[t] += u;
    __syncthreads();
  }
  bbase[t] = tmp[t] - v;
  bcur[t]  = tmp[t] - v;
}

__global__ __launch_bounds__(256) void k_bfill(const int* __restrict__ eidx, int E,
                                               const int* __restrict__ blockhist,
                                               int* bcur, u32* bdata) {
  __shared__ int base[512];
  __shared__ int hist[512];
  int t = threadIdx.x;
  const int* bh = blockhist + blockIdx.x * 512;
  for (int j = t; j < 512; j += 256) {
    int c = bh[j];
    base[j] = c ? atomicAdd(&bcur[j], c) : 0;
    hist[j] = 0;
  }
  __syncthreads();
  int e0 = blockIdx.x * 8192;
  int e1 = min(e0 + 8192, E);
  for (int e = e0 + t; e < e1; e += 256) {
    int src = eidx[e];
    int tgt = eidx[E + e];
    int b = tgt >> 8;
    int idx = atomicAdd(&hist[b], 1);
    bdata[base[b] + idx] = ((u32)src << 8) | (u32)(tgt & 255);
  }
}

// One block per bucket: histogram -> deg/dinv/ptr, LDS scan, LDS scatter, seq write.
__global__ __launch_bounds__(256) void k_csr(const u32* __restrict__ bdata,
                                             const int* __restrict__ bbase,
                                             const int* __restrict__ bcnt,
                                             int* __restrict__ deg, float* __restrict__ dinv,
                                             int* __restrict__ ptr, int* __restrict__ crow,
                                             int N) {
  __shared__ int lds[8192];
  __shared__ int hist[256];
  __shared__ int tmp[256];
  __shared__ int cur[256];
  int b = blockIdx.x, t = threadIdx.x;
  int node0 = b << 8;
  int ncnt = min(256, N - node0);
  hist[t] = 0;
  __syncthreads();
  int base = bbase[b], cnt = bcnt[b];
  for (int e = t; e < cnt; e += 256) atomicAdd(&hist[bdata[base + e] & 255], 1);
  __syncthreads();
  int h = hist[t];
  if (t < ncnt) {
    deg[node0 + t] = h + 1;
    dinv[node0 + t] = 1.0f / sqrtf((float)(h + 1));
  }
  tmp[t] = h; __syncthreads();
  for (int off = 1; off < 256; off <<= 1) {
    int u = (t >= off) ? tmp[t - off] : 0;
    __syncthreads();
    tmp[t] += u;
    __syncthreads();
  }
  int excl = tmp[t] - h;
  if (t < ncnt) ptr[node0 + t] = base + excl;
  cur[t] = excl;
  __syncthreads();
  for (int e = t; e < cnt; e += 256) {
    u32 pk = bdata[base + e];
    int pos = atomicAdd(&cur[pk & 255], 1);
    if (pos < 8192) lds[pos] = (int)(pk >> 8);
  }
  __syncthreads();
  for (int j = t; j < cnt; j += 256) crow[base + j] = lds[j];
}

// ---------------- transform: out[r,:] = dinv[r] * (in[r,:] @ W)  (MFMA, bf16)
__global__ __launch_bounds__(256) void k_xform(const void* __restrict__ in, int inbf,
                                               const int* __restrict__ flagp,
                                               const u16* __restrict__ wT,
                                               const float* __restrict__ dinv,
                                               u16* __restrict__ out, int N) {
  __shared__ __align__(16) u16 ws[64 * 72];
  int t = threadIdx.x;
  #pragma unroll
  for (int f = t; f < 512; f += 256) {
    int n = f >> 3, o = f & 7;
    *(float4*)&ws[n * 72 + o * 8] = ((const float4*)wT)[f];
  }
  __syncthreads();
  int fl = inbf ? 1 : *flagp;
  int lane = t & 63, wid = t >> 6;
  int g = lane >> 4, c = lane & 15;
  int arow = blockIdx.x * 64 + wid * 16 + c;
  short8 a0 = {0, 0, 0, 0, 0, 0, 0, 0}, a1 = {0, 0, 0, 0, 0, 0, 0, 0};
  if (arow < N) {
    if (fl) {
      const u16* p = (const u16*)in + (size_t)arow * 64 + g * 8;
      a0 = *(const short8*)p;
      a1 = *(const short8*)(p + 32);
    } else {
      const float* p = (const float*)in + (size_t)arow * 64 + g * 8;
      u16 tmpv[16];
      #pragma unroll
      for (int j = 0; j < 8; j++) tmpv[j] = f2bf(p[j]);
      #pragma unroll
      for (int j = 0; j < 8; j++) tmpv[8 + j] = f2bf(p[32 + j]);
      a0 = *(short8*)tmpv;
      a1 = *(short8*)(tmpv + 8);
    }
  }
  int rbase = blockIdx.x * 64 + wid * 16 + g * 4;
  float dv[4];
  #pragma unroll
  for (int r = 0; r < 4; r++) dv[r] = (rbase + r < N) ? dinv[rbase + r] : 0.f;
  #pragma unroll
  for (int tile = 0; tile < 4; tile++) {
    short8 b0 = *(const short8*)&ws[(tile * 16 + c) * 72 + g * 8];
    short8 b1 = *(const short8*)&ws[(tile * 16 + c) * 72 + g * 8 + 32];
    f32x4 z = {0.f, 0.f, 0.f, 0.f};
    f32x4 acc = __builtin_amdgcn_mfma_f32_16x16x32_bf16(a0, b0, z, 0, 0, 0);
    acc = __builtin_amdgcn_mfma_f32_16x16x32_bf16(a1, b1, acc, 0, 0, 0);
    #pragma unroll
    for (int r = 0; r < 4; r++) {
      int orow = rbase + r;
      if (orow < N) out[(size_t)orow * 64 + tile * 16 + c] = f2bf(acc[r] * dv[r]);
    }
  }
}

// ---------------- aggregation: dst[i,:] = relu(dinv[i]*(sum of pre-scaled rows) + b)
// wave = 1 node; 8 subgroups of 8 lanes; lane loads uint4 (8 bf16 feats).
// NOTE (R7 lesson): do NOT fuse this into MFMA-tile blocks -- the gather is
// latency-hidden by wave count (100K waves here vs 6K fused = 2x slower).
__global__ __launch_bounds__(256) void k_agg(const u16* __restrict__ src, u16* __restrict__ dst,
                                             const int* __restrict__ csr_row,
                                             const int* __restrict__ csr_ptr,
                                             const int* __restrict__ deg,
                                             const float* __restrict__ dinv,
                                             const float* __restrict__ bias, int N) {
  int lane = threadIdx.x & 63;
  int wid = threadIdx.x >> 6;
  int i = blockIdx.x * 4 + wid;
  if (i >= N) return;
  int sub = lane >> 3;                 // 0..7: edge slot
  int fo  = lane & 7;                  // feature octet: feats 8*fo .. 8*fo+7
  int start = csr_ptr[i];
  int total = deg[i];
  const u16* base = src + (size_t)fo * 8;
  float a0 = 0.f, a1 = 0.f, a2 = 0.f, a3 = 0.f;
  float a4 = 0.f, a5 = 0.f, a6 = 0.f, a7 = 0.f;
  #pragma unroll 4
  for (int t = sub; t < total; t += 8) {
    int r = (t == 0) ? i : csr_row[start + t - 1];
    uint4 v = *(const uint4*)(base + (size_t)r * 64);
    a0 += __uint_as_float(v.x << 16);
    a1 += __uint_as_float(v.x & 0xffff0000u);
    a2 += __uint_as_float(v.y << 16);
    a3 += __uint_as_float(v.y & 0xffff0000u);
    a4 += __uint_as_float(v.z << 16);
    a5 += __uint_as_float(v.z & 0xffff0000u);
    a6 += __uint_as_float(v.w << 16);
    a7 += __uint_as_float(v.w & 0xffff0000u);
  }
  #pragma unroll
  for (int off = 8; off < 64; off <<= 1) {
    a0 += __shfl_xor(a0, off); a1 += __shfl_xor(a1, off);
    a2 += __shfl_xor(a2, off); a3 += __shfl_xor(a3, off);
    a4 += __shfl_xor(a4, off); a5 += __shfl_xor(a5, off);
    a6 += __shfl_xor(a6, off); a7 += __shfl_xor(a7, off);
  }
  if (sub == 0) {
    float di = dinv[i];
    float4 b0 = ((const float4*)bias)[2 * fo];
    float4 b1 = ((const float4*)bias)[2 * fo + 1];
    u16 o[8];
    o[0] = f2bf(fmaxf(fmaf(a0, di, b0.x), 0.f));
    o[1] = f2bf(fmaxf(fmaf(a1, di, b0.y), 0.f));
    o[2] = f2bf(fmaxf(fmaf(a2, di, b0.z), 0.f));
    o[3] = f2bf(fmaxf(fmaf(a3, di, b0.w), 0.f));
    o[4] = f2bf(fmaxf(fmaf(a4, di, b1.x), 0.f));
    o[5] = f2bf(fmaxf(fmaf(a5, di, b1.y), 0.f));
    o[6] = f2bf(fmaxf(fmaf(a6, di, b1.z), 0.f));
    o[7] = f2bf(fmaxf(fmaf(a7, di, b1.w), 0.f));
    *(uint4*)&dst[(size_t)i * 64 + fo * 8] = *(uint4*)o;
  }
}

// ----------------------------- fused fc1(relu)+fc2 + ssq via MFMA (wave = 16 nodes)
__global__ __launch_bounds__(256) void k_fc(const u16* __restrict__ h,
                                            const u16* __restrict__ fc1T,
                                            const float* __restrict__ wf,
                                            float* __restrict__ outf,
                                            float* __restrict__ ssum, int N) {
  __shared__ __align__(16) u16 ws[256 * 72];
  __shared__ float red[16];
  int t = threadIdx.x;
  #pragma unroll
  for (int f = t; f < 2048; f += 256) {
    int n = f >> 3, o = f & 7;
    *(float4*)&ws[n * 72 + o * 8] = ((const float4*)fc1T)[f];
  }
  __syncthreads();
  int lane = t & 63, wid = t >> 6;
  int g = lane >> 4, c = lane & 15;
  int arow = blockIdx.x * 64 + wid * 16 + c;
  short8 a0 = {0, 0, 0, 0, 0, 0, 0, 0}, a1 = {0, 0, 0, 0, 0, 0, 0, 0};
  if (arow < N) {
    a0 = *(const short8*)&h[(size_t)arow * 64 + g * 8];
    a1 = *(const short8*)&h[(size_t)arow * 64 + g * 8 + 32];
  }
  float psum[4] = {0.f, 0.f, 0.f, 0.f};
  #pragma unroll
  for (int tile = 0; tile < 16; tile++) {
    short8 b0 = *(const short8*)&ws[(tile * 16 + c) * 72 + g * 8];
    short8 b1 = *(const short8*)&ws[(tile * 16 + c) * 72 + g * 8 + 32];
    f32x4 z = {0.f, 0.f, 0.f, 0.f};
    f32x4 acc = __builtin_amdgcn_mfma_f32_16x16x32_bf16(a0, b0, z, 0, 0, 0);
    acc = __builtin_amdgcn_mfma_f32_16x16x32_bf16(a1, b1, acc, 0, 0, 0);
    int col = tile * 16 + c;
    float fb = wf[128 + col];
    float fw = wf[384 + col];
    #pragma unroll
    for (int r = 0; r < 4; r++) psum[r] += fmaxf(acc[r] + fb, 0.f) * fw;
  }
  #pragma unroll
  for (int off = 1; off < 16; off <<= 1) {
    #pragma unroll
    for (int r = 0; r < 4; r++) psum[r] += __shfl_xor(psum[r], off);
  }
  float fc2b = wf[640];
  if (c == 0) {
    float ss = 0.f;
    int rbase = blockIdx.x * 64 + wid * 16 + g * 4;
    #pragma unroll
    for (int r = 0; r < 4; r++) {
      int row = rbase + r;
      if (row < N) {
        float o = psum[r] + fc2b;
        outf[row] = o;
        ss += o * o;
      }
    }
    red[wid * 4 + g] = ss;
  }
  __syncthreads();
  if (t == 0) {
    float s = 0.f;
    #pragma unroll
    for (int j = 0; j < 16; j++) s += red[j];
    atomicAdd(ssum, s);
  }
}

// ------------------------------------------------------------- L2 norm write
__global__ void k_norm(const float* __restrict__ outf, const float* __restrict__ ssum,
                       void* dout, int N, const int* flag) {
  int i = blockIdx.x * blockDim.x + threadIdx.x;
  if (i >= N) return;
  float denom = fmaxf(sqrtf(*ssum), 1e-12f);
  float v = outf[i] / denom;
  if (*flag) ((__hip_bfloat16*)dout)[i] = __float2bfloat16(v);
  else       ((float*)dout)[i] = v;
}

extern "C" void kernel_launch(void* const* d_in, const int* in_sizes, int n_in,
                              void* d_out, int out_size, void* d_ws, size_t ws_size,
                              hipStream_t stream) {
  const void* x   = d_in[0];
  const int* eidx = (const int*)d_in[1];
  const void* W1  = d_in[2]; const void* b1  = d_in[3];
  const void* W2  = d_in[4]; const void* b2  = d_in[5];
  const void* f1w = d_in[6]; const void* f1b = d_in[7];
  const void* f2w = d_in[8]; const void* f2b = d_in[9];
  int N = in_sizes[0] / 64;
  int E = in_sizes[1] / 2;
  int NB = (N + 255) >> 8;           // 256-node buckets
  int GEB = (E + 8191) / 8192;

  char* ws = (char*)d_ws;
  size_t off = 0;
  auto alloc = [&](size_t b) {
    void* p = ws + off;
    off = (off + b + 255) & ~(size_t)255;
    return p;
  };
  int*   flag  = (int*)  alloc(4);
  float* ssum  = (float*)alloc(4);
  int*   bcnt  = (int*)  alloc(512 * 4);
  int*   bbase = (int*)  alloc(512 * 4);
  int*   bcur  = (int*)  alloc(512 * 4);
  int*   bhist = (int*)  alloc((size_t)GEB * 512 * 4);
  u32*   bdata = (u32*)  alloc((size_t)E * 4);
  int*   deg   = (int*)  alloc((size_t)N * 4);
  int*   ptr   = (int*)  alloc((size_t)N * 4);
  float* dinv  = (float*)alloc((size_t)N * 4);
  int*   crow  = (int*)  alloc((size_t)E * 4);
  u16*   wbh   = (u16*)  alloc(24576 * 2);
  float* wbf   = (float*)alloc(641 * 4);
  u16*   HA    = (u16*)  alloc((size_t)N * 64 * 2);
  u16*   HT    = (u16*)  alloc((size_t)N * 64 * 2);
  float* outf  = (float*)alloc((size_t)N * 4);

  int GN = (N + 255) / 256;
  int NT = (N + 63) / 64;

  k_flag<<<1, 256, 0, stream>>>(x, flag, ssum, bcnt);
  k_conv_w<<<(24576 + 641 + 255) / 256, 256, 0, stream>>>(W1, b1, W2, b2, f1w, f1b, f2w, f2b,
                                                          wbh, wbf, flag);
  // CSR build (bucketed, 256-node buckets)
  k_bcount<<<GEB, 256, 0, stream>>>(eidx, E, bcnt, bhist);
  k_bscan<<<1, 512, 0, stream>>>(bcnt, bbase, bcur);
  k_bfill<<<GEB, 256, 0, stream>>>(eidx, E, bhist, bcur, bdata);
  k_csr<<<NB, 256, 0, stream>>>(bdata, bbase, bcnt, deg, dinv, ptr, crow, N);

  // conv1 (reads raw x, converts inline)
  k_xform<<<NT, 256, 0, stream>>>(x, 0, flag, wbh + 0, dinv, HT, N);
  k_agg<<<(N + 3) / 4, 256, 0, stream>>>(HT, HA, crow, ptr, deg, dinv, wbf + 0, N);
  // conv2
  k_xform<<<NT, 256, 0, stream>>>(HA, 1, flag, wbh + 4096, dinv, HT, N);
  k_agg<<<(N + 3) / 4, 256, 0, stream>>>(HT, HA, crow, ptr, deg, dinv, wbf + 64, N);
  // fused MLP + sum of squares
  k_fc<<<NT, 256, 0, stream>>>(HA, wbh + 8192, wbf, outf, ssum, N);
  // normalize + write
  k_norm<<<GN, 256, 0, stream>>>(outf, ssum, d_out, N, flag);
}

// Round 10
// 275.809 us; speedup vs baseline: 1.1280x; 1.0563x over previous
//
#include <hip/hip_runtime.h>
#include <hip/hip_bf16.h>

typedef unsigned short u16;
typedef unsigned int u32;
typedef __attribute__((ext_vector_type(8))) short short8;
typedef __attribute__((ext_vector_type(4))) float f32x4;

__device__ __forceinline__ float bf2f(u16 h) {
  return __uint_as_float(((u32)h) << 16);
}
__device__ __forceinline__ float ldconv(const void* p, int i, int fl) {
  return fl ? bf2f(((const u16*)p)[i]) : ((const float*)p)[i];
}
__device__ __forceinline__ u16 f2bf(float v) {
  __hip_bfloat16 h = __float2bfloat16(v);
  return *(u16*)&h;
}

// ---------------------------------------------------------------- dtype sniff
__global__ void k_flag(const void* x, int* flag, float* ssum, int* bcnt) {
  __shared__ float red[256];
  int t = threadIdx.x;
  const u16* h = (const u16*)x;
  float m = 0.f;
  for (int i = t; i < 1024; i += 256) m = fmaxf(m, fabsf(bf2f(h[i])));
  red[t] = m; __syncthreads();
  for (int off = 128; off > 0; off >>= 1) {
    if (t < off) red[t] = fmaxf(red[t], red[t + off]);
    __syncthreads();
  }
  bcnt[t] = 0; bcnt[t + 256] = 0;
  if (t == 0) { *flag = (red[0] < 1000.0f) ? 1 : 0; *ssum = 0.f; }
}

// ------------------------------------------------------- weight conversion
// wbh (u16): W1T [0,4096) W2T [4096,8192) fc1T [8192,24576)   (all [n][k], k=64)
// wbf (f32): b1[0,64) b2[64,128) fc1b[128,384) fc2w[384,640) fc2b[640]
__global__ void k_conv_w(const void* W1, const void* b1, const void* W2, const void* b2,
                         const void* f1w, const void* f1b, const void* f2w, const void* f2b,
                         u16* wbh, float* wbf, const int* flag) {
  int fl = *flag;
  int i = blockIdx.x * blockDim.x + threadIdx.x;
  if (i < 4096) {
    int n = i >> 6, k = i & 63;
    wbh[i] = f2bf(ldconv(W1, k * 64 + n, fl));
  } else if (i < 8192) {
    int j = i - 4096; int n = j >> 6, k = j & 63;
    wbh[i] = f2bf(ldconv(W2, k * 64 + n, fl));
  } else if (i < 24576) {
    int j = i - 8192; int n = j >> 6, k = j & 63;
    wbh[i] = f2bf(ldconv(f1w, k * 256 + n, fl));
  } else if (i < 24576 + 641) {
    int j = i - 24576;
    float v;
    if (j < 64)       v = ldconv(b1,  j,       fl);
    else if (j < 128) v = ldconv(b2,  j - 64,  fl);
    else if (j < 384) v = ldconv(f1b, j - 128, fl);
    else if (j < 640) v = ldconv(f2w, j - 384, fl);
    else              v = ldconv(f2b, 0,       fl);
    wbf[j] = v;
  }
}

// --------------------------------------- bucketed CSR build (256-node buckets)
__global__ __launch_bounds__(256) void k_bcount(const int* __restrict__ eidx, int E,
                                                int* bcnt, int* blockhist) {
  __shared__ int hist[512];
  int t = threadIdx.x;
  hist[t] = 0; hist[t + 256] = 0;
  __syncthreads();
  int e0 = blockIdx.x * 8192;
  int e1 = min(e0 + 8192, E);
  for (int e = e0 + t; e < e1; e += 256) atomicAdd(&hist[eidx[E + e] >> 8], 1);
  __syncthreads();
  int* bh = blockhist + blockIdx.x * 512;
  for (int j = t; j < 512; j += 256) {
    bh[j] = hist[j];
    if (hist[j]) atomicAdd(&bcnt[j], hist[j]);
  }
}

__global__ void k_bscan(const int* __restrict__ bcnt, int* bbase, int* bcur) {
  __shared__ int tmp[512];
  int t = threadIdx.x;
  int v = bcnt[t];
  tmp[t] = v; __syncthreads();
  for (int off = 1; off < 512; off <<= 1) {
    int u = (t >= off) ? tmp[t - off] : 0;
    __syncthreads();
    tmp[t] += u;
    __syncthreads();
  }
  bbase[t] = tmp[t] - v;
  bcur[t]  = tmp[t] - v;
}

__global__ __launch_bounds__(256) void k_bfill(const int* __restrict__ eidx, int E,
                                               const int* __restrict__ blockhist,
                                               int* bcur, u32* bdata) {
  __shared__ int base[512];
  __shared__ int hist[512];
  int t = threadIdx.x;
  const int* bh = blockhist + blockIdx.x * 512;
  for (int j = t; j < 512; j += 256) {
    int c = bh[j];
    base[j] = c ? atomicAdd(&bcur[j], c) : 0;
    hist[j] = 0;
  }
  __syncthreads();
  int e0 = blockIdx.x * 8192;
  int e1 = min(e0 + 8192, E);
  for (int e = e0 + t; e < e1; e += 256) {
    int src = eidx[e];
    int tgt = eidx[E + e];
    int b = tgt >> 8;
    int idx = atomicAdd(&hist[b], 1);
    bdata[base[b] + idx] = ((u32)src << 8) | (u32)(tgt & 255);
  }
}

// One block per bucket: histogram -> deg/dinv/ptr, LDS scan, LDS scatter, seq write.
__global__ __launch_bounds__(256) void k_csr(const u32* __restrict__ bdata,
                                             const int* __restrict__ bbase,
                                             const int* __restrict__ bcnt,
                                             int* __restrict__ deg, float* __restrict__ dinv,
                                             int* __restrict__ ptr, int* __restrict__ crow,
                                             int N) {
  __shared__ int lds[8192];
  __shared__ int hist[256];
  __shared__ int tmp[256];
  __shared__ int cur[256];
  int b = blockIdx.x, t = threadIdx.x;
  int node0 = b << 8;
  int ncnt = min(256, N - node0);
  hist[t] = 0;
  __syncthreads();
  int base = bbase[b], cnt = bcnt[b];
  for (int e = t; e < cnt; e += 256) atomicAdd(&hist[bdata[base + e] & 255], 1);
  __syncthreads();
  int h = hist[t];
  if (t < ncnt) {
    deg[node0 + t] = h + 1;
    dinv[node0 + t] = 1.0f / sqrtf((float)(h + 1));
  }
  tmp[t] = h; __syncthreads();
  for (int off = 1; off < 256; off <<= 1) {
    int u = (t >= off) ? tmp[t - off] : 0;
    __syncthreads();
    tmp[t] += u;
    __syncthreads();
  }
  int excl = tmp[t] - h;
  if (t < ncnt) ptr[node0 + t] = base + excl;
  cur[t] = excl;
  __syncthreads();
  for (int e = t; e < cnt; e += 256) {
    u32 pk = bdata[base + e];
    int pos = atomicAdd(&cur[pk & 255], 1);
    if (pos < 8192) lds[pos] = (int)(pk >> 8);
  }
  __syncthreads();
  for (int j = t; j < cnt; j += 256) crow[base + j] = lds[j];
}

// ---------------- transform: out[r,:] = dinv[r] * (in[r,:] @ W)  (MFMA, bf16)
__global__ __launch_bounds__(256) void k_xform(const void* __restrict__ in, int inbf,
                                               const int* __restrict__ flagp,
                                               const u16* __restrict__ wT,
                                               const float* __restrict__ dinv,
                                               u16* __restrict__ out, int N) {
  __shared__ __align__(16) u16 ws[64 * 72];
  int t = threadIdx.x;
  #pragma unroll
  for (int f = t; f < 512; f += 256) {
    int n = f >> 3, o = f & 7;
    *(float4*)&ws[n * 72 + o * 8] = ((const float4*)wT)[f];
  }
  __syncthreads();
  int fl = inbf ? 1 : *flagp;
  int lane = t & 63, wid = t >> 6;
  int g = lane >> 4, c = lane & 15;
  int arow = blockIdx.x * 64 + wid * 16 + c;
  short8 a0 = {0, 0, 0, 0, 0, 0, 0, 0}, a1 = {0, 0, 0, 0, 0, 0, 0, 0};
  if (arow < N) {
    if (fl) {
      const u16* p = (const u16*)in + (size_t)arow * 64 + g * 8;
      a0 = *(const short8*)p;
      a1 = *(const short8*)(p + 32);
    } else {
      const float* p = (const float*)in + (size_t)arow * 64 + g * 8;
      u16 tmpv[16];
      #pragma unroll
      for (int j = 0; j < 8; j++) tmpv[j] = f2bf(p[j]);
      #pragma unroll
      for (int j = 0; j < 8; j++) tmpv[8 + j] = f2bf(p[32 + j]);
      a0 = *(short8*)tmpv;
      a1 = *(short8*)(tmpv + 8);
    }
  }
  int rbase = blockIdx.x * 64 + wid * 16 + g * 4;
  float dv[4];
  #pragma unroll
  for (int r = 0; r < 4; r++) dv[r] = (rbase + r < N) ? dinv[rbase + r] : 0.f;
  #pragma unroll
  for (int tile = 0; tile < 4; tile++) {
    short8 b0 = *(const short8*)&ws[(tile * 16 + c) * 72 + g * 8];
    short8 b1 = *(const short8*)&ws[(tile * 16 + c) * 72 + g * 8 + 32];
    f32x4 z = {0.f, 0.f, 0.f, 0.f};
    f32x4 acc = __builtin_amdgcn_mfma_f32_16x16x32_bf16(a0, b0, z, 0, 0, 0);
    acc = __builtin_amdgcn_mfma_f32_16x16x32_bf16(a1, b1, acc, 0, 0, 0);
    #pragma unroll
    for (int r = 0; r < 4; r++) {
      int orow = rbase + r;
      if (orow < N) out[(size_t)orow * 64 + tile * 16 + c] = f2bf(acc[r] * dv[r]);
    }
  }
}

// ---------------- aggregation (wave = 1 node; 8 subgroups x uint4)
// post=1 (conv1): dst = bf16( dinv_i * relu(dinv_i*sum + bias) )  [pre-scaled for conv2]
// post=0 (conv2): dst = bf16( sum )                               [W2 deferred to k_xfc]
// NOTE (R7 lesson): do NOT fuse this into MFMA-tile blocks -- the gather is
// latency-hidden by wave count (100K waves here vs 6K fused = 2x slower).
__global__ __launch_bounds__(256) void k_agg(const u16* __restrict__ src, u16* __restrict__ dst,
                                             const int* __restrict__ csr_row,
                                             const int* __restrict__ csr_ptr,
                                             const int* __restrict__ deg,
                                             const float* __restrict__ dinv,
                                             const float* __restrict__ bias, int post, int N) {
  int lane = threadIdx.x & 63;
  int wid = threadIdx.x >> 6;
  int i = blockIdx.x * 4 + wid;
  if (i >= N) return;
  int sub = lane >> 3;                 // 0..7: edge slot
  int fo  = lane & 7;                  // feature octet: feats 8*fo .. 8*fo+7
  int start = csr_ptr[i];
  int total = deg[i];
  const u16* base = src + (size_t)fo * 8;
  float a0 = 0.f, a1 = 0.f, a2 = 0.f, a3 = 0.f;
  float a4 = 0.f, a5 = 0.f, a6 = 0.f, a7 = 0.f;
  #pragma unroll 4
  for (int t = sub; t < total; t += 8) {
    int r = (t == 0) ? i : csr_row[start + t - 1];
    uint4 v = *(const uint4*)(base + (size_t)r * 64);
    a0 += __uint_as_float(v.x << 16);
    a1 += __uint_as_float(v.x & 0xffff0000u);
    a2 += __uint_as_float(v.y << 16);
    a3 += __uint_as_float(v.y & 0xffff0000u);
    a4 += __uint_as_float(v.z << 16);
    a5 += __uint_as_float(v.z & 0xffff0000u);
    a6 += __uint_as_float(v.w << 16);
    a7 += __uint_as_float(v.w & 0xffff0000u);
  }
  #pragma unroll
  for (int off = 8; off < 64; off <<= 1) {
    a0 += __shfl_xor(a0, off); a1 += __shfl_xor(a1, off);
    a2 += __shfl_xor(a2, off); a3 += __shfl_xor(a3, off);
    a4 += __shfl_xor(a4, off); a5 += __shfl_xor(a5, off);
    a6 += __shfl_xor(a6, off); a7 += __shfl_xor(a7, off);
  }
  if (sub == 0) {
    u16 o[8];
    if (post) {
      float di = dinv[i];
      float4 b0 = ((const float4*)bias)[2 * fo];
      float4 b1 = ((const float4*)bias)[2 * fo + 1];
      o[0] = f2bf(di * fmaxf(fmaf(a0, di, b0.x), 0.f));
      o[1] = f2bf(di * fmaxf(fmaf(a1, di, b0.y), 0.f));
      o[2] = f2bf(di * fmaxf(fmaf(a2, di, b0.z), 0.f));
      o[3] = f2bf(di * fmaxf(fmaf(a3, di, b0.w), 0.f));
      o[4] = f2bf(di * fmaxf(fmaf(a4, di, b1.x), 0.f));
      o[5] = f2bf(di * fmaxf(fmaf(a5, di, b1.y), 0.f));
      o[6] = f2bf(di * fmaxf(fmaf(a6, di, b1.z), 0.f));
      o[7] = f2bf(di * fmaxf(fmaf(a7, di, b1.w), 0.f));
    } else {
      o[0] = f2bf(a0); o[1] = f2bf(a1); o[2] = f2bf(a2); o[3] = f2bf(a3);
      o[4] = f2bf(a4); o[5] = f2bf(a5); o[6] = f2bf(a6); o[7] = f2bf(a7);
    }
    *(uint4*)&dst[(size_t)i * 64 + fo * 8] = *(uint4*)o;
  }
}

// -------- fused: T = relu(dinv_i*(S @ W2) + b2); fc1(relu); fc2; ssq  (MFMA)
// T round-trips via a wave-local LDS rows buffer (C-layout -> A-layout),
// pattern verified in R7's k_aggfc. fc1 staged in 2 phases of 128 cols.
__global__ __launch_bounds__(256) void k_xfc(const u16* __restrict__ S,
                                             const u16* __restrict__ w2T,
                                             const u16* __restrict__ fc1T,
                                             const float* __restrict__ wf,
                                             const float* __restrict__ dinv,
                                             float* __restrict__ outf,
                                             float* __restrict__ ssum, int N) {
  __shared__ __align__(16) u16 w2s[64 * 72];    // 9216 B
  __shared__ __align__(16) u16 rows[64 * 72];   // 9216 B (T, bf16)
  __shared__ __align__(16) u16 f1s[128 * 72];   // 18432 B (fc1 phase)
  __shared__ float red[16];
  int t = threadIdx.x;
  #pragma unroll
  for (int f = t; f < 512; f += 256) {
    int n = f >> 3, o = f & 7;
    *(float4*)&w2s[n * 72 + o * 8] = ((const float4*)w2T)[f];
  }
  __syncthreads();
  int lane = t & 63, wid = t >> 6;
  int g = lane >> 4, c = lane & 15;
  int arow = blockIdx.x * 64 + wid * 16 + c;
  short8 a0 = {0, 0, 0, 0, 0, 0, 0, 0}, a1 = {0, 0, 0, 0, 0, 0, 0, 0};
  if (arow < N) {
    a0 = *(const short8*)&S[(size_t)arow * 64 + g * 8];
    a1 = *(const short8*)&S[(size_t)arow * 64 + g * 8 + 32];
  }
  int rbase = blockIdx.x * 64 + wid * 16 + g * 4;
  float dv[4];
  #pragma unroll
  for (int r = 0; r < 4; r++) dv[r] = (rbase + r < N) ? dinv[rbase + r] : 0.f;
  // W2 transform -> T (bf16) into wave-local rows buffer
  #pragma unroll
  for (int tile = 0; tile < 4; tile++) {
    short8 b0 = *(const short8*)&w2s[(tile * 16 + c) * 72 + g * 8];
    short8 b1 = *(const short8*)&w2s[(tile * 16 + c) * 72 + g * 8 + 32];
    f32x4 z = {0.f, 0.f, 0.f, 0.f};
    f32x4 acc = __builtin_amdgcn_mfma_f32_16x16x32_bf16(a0, b0, z, 0, 0, 0);
    acc = __builtin_amdgcn_mfma_f32_16x16x32_bf16(a1, b1, acc, 0, 0, 0);
    int col = tile * 16 + c;
    float b2v = wf[64 + col];
    #pragma unroll
    for (int r = 0; r < 4; r++) {
      float tv = fmaxf(fmaf(acc[r], dv[r], b2v), 0.f);
      rows[(wid * 16 + g * 4 + r) * 72 + col] = f2bf(tv);
    }
  }
  // A-frags for fc1 from own wave's rows (wave-local; lgkmcnt handled by compiler)
  short8 t0 = *(const short8*)&rows[(wid * 16 + c) * 72 + g * 8];
  short8 t1 = *(const short8*)&rows[(wid * 16 + c) * 72 + g * 8 + 32];
  float psum[4] = {0.f, 0.f, 0.f, 0.f};
  for (int ph = 0; ph < 2; ph++) {
    __syncthreads();
    #pragma unroll
    for (int f = t; f < 1024; f += 256) {
      int n = f >> 3, o = f & 7;
      *(float4*)&f1s[n * 72 + o * 8] = ((const float4*)(fc1T + ph * 8192))[f];
    }
    __syncthreads();
    #pragma unroll
    for (int tile = 0; tile < 8; tile++) {
      short8 b0 = *(const short8*)&f1s[(tile * 16 + c) * 72 + g * 8];
      short8 b1 = *(const short8*)&f1s[(tile * 16 + c) * 72 + g * 8 + 32];
      f32x4 z = {0.f, 0.f, 0.f, 0.f};
      f32x4 acc = __builtin_amdgcn_mfma_f32_16x16x32_bf16(t0, b0, z, 0, 0, 0);
      acc = __builtin_amdgcn_mfma_f32_16x16x32_bf16(t1, b1, acc, 0, 0, 0);
      int col = ph * 128 + tile * 16 + c;
      float fb = wf[128 + col];
      float fw = wf[384 + col];
      #pragma unroll
      for (int r = 0; r < 4; r++) psum[r] += fmaxf(acc[r] + fb, 0.f) * fw;
    }
  }
  #pragma unroll
  for (int off = 1; off < 16; off <<= 1) {
    #pragma unroll
    for (int r = 0; r < 4; r++) psum[r] += __shfl_xor(psum[r], off);
  }
  float fc2b = wf[640];
  if (c == 0) {
    float ss = 0.f;
    #pragma unroll
    for (int r = 0; r < 4; r++) {
      int row = rbase + r;
      if (row < N) {
        float o = psum[r] + fc2b;
        outf[row] = o;
        ss += o * o;
      }
    }
    red[wid * 4 + g] = ss;
  }
  __syncthreads();
  if (t == 0) {
    float s = 0.f;
    #pragma unroll
    for (int j = 0; j < 16; j++) s += red[j];
    atomicAdd(ssum, s);
  }
}

// ------------------------------------------------------------- L2 norm write
__global__ void k_norm(const float* __restrict__ outf, const float* __restrict__ ssum,
                       void* dout, int N, const int* flag) {
  int i = blockIdx.x * blockDim.x + threadIdx.x;
  if (i >= N) return;
  float denom = fmaxf(sqrtf(*ssum), 1e-12f);
  float v = outf[i] / denom;
  if (*flag) ((__hip_bfloat16*)dout)[i] = __float2bfloat16(v);
  else       ((float*)dout)[i] = v;
}

extern "C" void kernel_launch(void* const* d_in, const int* in_sizes, int n_in,
                              void* d_out, int out_size, void* d_ws, size_t ws_size,
                              hipStream_t stream) {
  const void* x   = d_in[0];
  const int* eidx = (const int*)d_in[1];
  const void* W1  = d_in[2]; const void* b1  = d_in[3];
  const void* W2  = d_in[4]; const void* b2  = d_in[5];
  const void* f1w = d_in[6]; const void* f1b = d_in[7];
  const void* f2w = d_in[8]; const void* f2b = d_in[9];
  int N = in_sizes[0] / 64;
  int E = in_sizes[1] / 2;
  int NB = (N + 255) >> 8;           // 256-node buckets
  int GEB = (E + 8191) / 8192;

  char* ws = (char*)d_ws;
  size_t off = 0;
  auto alloc = [&](size_t b) {
    void* p = ws + off;
    off = (off + b + 255) & ~(size_t)255;
    return p;
  };
  int*   flag  = (int*)  alloc(4);
  float* ssum  = (float*)alloc(4);
  int*   bcnt  = (int*)  alloc(512 * 4);
  int*   bbase = (int*)  alloc(512 * 4);
  int*   bcur  = (int*)  alloc(512 * 4);
  int*   bhist = (int*)  alloc((size_t)GEB * 512 * 4);
  u32*   bdata = (u32*)  alloc((size_t)E * 4);
  int*   deg   = (int*)  alloc((size_t)N * 4);
  int*   ptr   = (int*)  alloc((size_t)N * 4);
  float* dinv  = (float*)alloc((size_t)N * 4);
  int*   crow  = (int*)  alloc((size_t)E * 4);
  u16*   wbh   = (u16*)  alloc(24576 * 2);
  float* wbf   = (float*)alloc(641 * 4);
  u16*   HA    = (u16*)  alloc((size_t)N * 64 * 2);
  u16*   HT    = (u16*)  alloc((size_t)N * 64 * 2);
  float* outf  = (float*)alloc((size_t)N * 4);

  int GN = (N + 255) / 256;
  int NT = (N + 63) / 64;

  k_flag<<<1, 256, 0, stream>>>(x, flag, ssum, bcnt);
  k_conv_w<<<(24576 + 641 + 255) / 256, 256, 0, stream>>>(W1, b1, W2, b2, f1w, f1b, f2w, f2b,
                                                          wbh, wbf, flag);
  // CSR build (bucketed, 256-node buckets)
  k_bcount<<<GEB, 256, 0, stream>>>(eidx, E, bcnt, bhist);
  k_bscan<<<1, 512, 0, stream>>>(bcnt, bbase, bcur);
  k_bfill<<<GEB, 256, 0, stream>>>(eidx, E, bhist, bcur, bdata);
  k_csr<<<NB, 256, 0, stream>>>(bdata, bbase, bcnt, deg, dinv, ptr, crow, N);

  // conv1 transform (reads raw x, converts inline): HT = dinv*(x@W1)
  k_xform<<<NT, 256, 0, stream>>>(x, 0, flag, wbh + 0, dinv, HT, N);
  // conv1 aggregate: HA = dinv * relu(dinv*sum + b1)   (pre-scaled for conv2)
  k_agg<<<(N + 3) / 4, 256, 0, stream>>>(HT, HA, crow, ptr, deg, dinv, wbf + 0, 1, N);
  // conv2 aggregate (pure sum, W2 deferred): HT = sum of HA rows
  k_agg<<<(N + 3) / 4, 256, 0, stream>>>(HA, HT, crow, ptr, deg, dinv, wbf, 0, N);
  // fused W2-transform + MLP + sum of squares
  k_xfc<<<NT, 256, 0, stream>>>(HT, wbh + 4096, wbh + 8192, wbf, dinv, outf, ssum, N);
  // normalize + write
  k_norm<<<GN, 256, 0, stream>>>(outf, ssum, d_out, N, flag);
}

// Round 11
// 275.171 us; speedup vs baseline: 1.1306x; 1.0023x over previous
//
#include <hip/hip_runtime.h>
#include <hip/hip_bf16.h>

typedef unsigned short u16;
typedef unsigned int u32;
typedef __attribute__((ext_vector_type(8))) short short8;
typedef __attribute__((ext_vector_type(4))) float f32x4;

__device__ __forceinline__ float bf2f(u16 h) {
  return __uint_as_float(((u32)h) << 16);
}
__device__ __forceinline__ float ldconv(const void* p, int i, int fl) {
  return fl ? bf2f(((const u16*)p)[i]) : ((const float*)p)[i];
}
__device__ __forceinline__ u16 f2bf(float v) {
  __hip_bfloat16 h = __float2bfloat16(v);
  return *(u16*)&h;
}

// ------------------- weight conversion + dtype sniff (R7-verified pattern)
// wbh (u16): W1T [0,4096) W2T [4096,8192) fc1T [8192,24576)   (all [n][k], k=64)
// wbf (f32): b1[0,64) b2[64,128) fc1b[128,384) fc2w[384,640) fc2b[640]
__global__ __launch_bounds__(256) void k_conv_w(const void* x,
                         const void* W1, const void* b1, const void* W2, const void* b2,
                         const void* f1w, const void* f1b, const void* f2w, const void* f2b,
                         u16* wbh, float* wbf, int* flag) {
  __shared__ float red[256];
  int t = threadIdx.x;
  // each block sniffs dtype independently (reads 2 KB of x, L2-resident)
  const u16* hx = (const u16*)x;
  float m = 0.f;
  for (int i = t; i < 1024; i += 256) m = fmaxf(m, fabsf(bf2f(hx[i])));
  red[t] = m; __syncthreads();
  for (int off = 128; off > 0; off >>= 1) {
    if (t < off) red[t] = fmaxf(red[t], red[t + off]);
    __syncthreads();
  }
  int fl = (red[0] < 1000.0f) ? 1 : 0;
  if (blockIdx.x == 0 && t == 0) *flag = fl;
  int i = blockIdx.x * 256 + t;
  if (i < 4096) {
    int n = i >> 6, k = i & 63;
    wbh[i] = f2bf(ldconv(W1, k * 64 + n, fl));
  } else if (i < 8192) {
    int j = i - 4096; int n = j >> 6, k = j & 63;
    wbh[i] = f2bf(ldconv(W2, k * 64 + n, fl));
  } else if (i < 24576) {
    int j = i - 8192; int n = j >> 6, k = j & 63;
    wbh[i] = f2bf(ldconv(f1w, k * 256 + n, fl));
  } else if (i < 24576 + 641) {
    int j = i - 24576;
    float v;
    if (j < 64)       v = ldconv(b1,  j,       fl);
    else if (j < 128) v = ldconv(b2,  j - 64,  fl);
    else if (j < 384) v = ldconv(f1b, j - 128, fl);
    else if (j < 640) v = ldconv(f2w, j - 384, fl);
    else              v = ldconv(f2b, 0,       fl);
    wbf[j] = v;
  }
}

// --------------------------------------- bucketed CSR build (256-node buckets)
// QUARANTINE NOTE (R8): this 4-kernel scan-based build is the verified one.
// The single-pass fixed-capacity variant intermittently corrupted results.
__global__ __launch_bounds__(256) void k_bcount(const int* __restrict__ eidx, int E,
                                                int* bcnt, int* blockhist) {
  __shared__ int hist[512];
  int t = threadIdx.x;
  hist[t] = 0; hist[t + 256] = 0;
  __syncthreads();
  int e0 = blockIdx.x * 8192;
  int e1 = min(e0 + 8192, E);
  for (int e = e0 + t; e < e1; e += 256) atomicAdd(&hist[eidx[E + e] >> 8], 1);
  __syncthreads();
  int* bh = blockhist + blockIdx.x * 512;
  for (int j = t; j < 512; j += 256) {
    bh[j] = hist[j];
    if (hist[j]) atomicAdd(&bcnt[j], hist[j]);
  }
}

__global__ void k_bscan(const int* __restrict__ bcnt, int* bbase, int* bcur) {
  __shared__ int tmp[512];
  int t = threadIdx.x;
  int v = bcnt[t];
  tmp[t] = v; __syncthreads();
  for (int off = 1; off < 512; off <<= 1) {
    int u = (t >= off) ? tmp[t - off] : 0;
    __syncthreads();
    tmp[t] += u;
    __syncthreads();
  }
  bbase[t] = tmp[t] - v;
  bcur[t]  = tmp[t] - v;
}

__global__ __launch_bounds__(256) void k_bfill(const int* __restrict__ eidx, int E,
                                               const int* __restrict__ blockhist,
                                               int* bcur, u32* bdata) {
  __shared__ int base[512];
  __shared__ int hist[512];
  int t = threadIdx.x;
  const int* bh = blockhist + blockIdx.x * 512;
  for (int j = t; j < 512; j += 256) {
    int c = bh[j];
    base[j] = c ? atomicAdd(&bcur[j], c) : 0;
    hist[j] = 0;
  }
  __syncthreads();
  int e0 = blockIdx.x * 8192;
  int e1 = min(e0 + 8192, E);
  for (int e = e0 + t; e < e1; e += 256) {
    int src = eidx[e];
    int tgt = eidx[E + e];
    int b = tgt >> 8;
    int idx = atomicAdd(&hist[b], 1);
    bdata[base[b] + idx] = ((u32)src << 8) | (u32)(tgt & 255);
  }
}

// One block per bucket: histogram -> deg/dinv/ptr, LDS scan, LDS scatter, seq write.
__global__ __launch_bounds__(256) void k_csr(const u32* __restrict__ bdata,
                                             const int* __restrict__ bbase,
                                             const int* __restrict__ bcnt,
                                             int* __restrict__ deg, float* __restrict__ dinv,
                                             int* __restrict__ ptr, int* __restrict__ crow,
                                             int N) {
  __shared__ int lds[8192];
  __shared__ int hist[256];
  __shared__ int tmp[256];
  __shared__ int cur[256];
  int b = blockIdx.x, t = threadIdx.x;
  int node0 = b << 8;
  int ncnt = min(256, N - node0);
  hist[t] = 0;
  __syncthreads();
  int base = bbase[b], cnt = bcnt[b];
  for (int e = t; e < cnt; e += 256) atomicAdd(&hist[bdata[base + e] & 255], 1);
  __syncthreads();
  int h = hist[t];
  if (t < ncnt) {
    deg[node0 + t] = h + 1;
    dinv[node0 + t] = 1.0f / sqrtf((float)(h + 1));
  }
  tmp[t] = h; __syncthreads();
  for (int off = 1; off < 256; off <<= 1) {
    int u = (t >= off) ? tmp[t - off] : 0;
    __syncthreads();
    tmp[t] += u;
    __syncthreads();
  }
  int excl = tmp[t] - h;
  if (t < ncnt) ptr[node0 + t] = base + excl;
  cur[t] = excl;
  __syncthreads();
  for (int e = t; e < cnt; e += 256) {
    u32 pk = bdata[base + e];
    int pos = atomicAdd(&cur[pk & 255], 1);
    if (pos < 8192) lds[pos] = (int)(pk >> 8);
  }
  __syncthreads();
  for (int j = t; j < cnt; j += 256) crow[base + j] = lds[j];
}

// ---------------- transform: out[r,:] = dinv[r] * (in[r,:] @ W)  (MFMA, bf16)
__global__ __launch_bounds__(256) void k_xform(const void* __restrict__ in, int inbf,
                                               const int* __restrict__ flagp,
                                               const u16* __restrict__ wT,
                                               const float* __restrict__ dinv,
                                               u16* __restrict__ out, int N) {
  __shared__ __align__(16) u16 ws[64 * 72];
  int t = threadIdx.x;
  #pragma unroll
  for (int f = t; f < 512; f += 256) {
    int n = f >> 3, o = f & 7;
    *(float4*)&ws[n * 72 + o * 8] = ((const float4*)wT)[f];
  }
  __syncthreads();
  int fl = inbf ? 1 : *flagp;
  int lane = t & 63, wid = t >> 6;
  int g = lane >> 4, c = lane & 15;
  int arow = blockIdx.x * 64 + wid * 16 + c;
  short8 a0 = {0, 0, 0, 0, 0, 0, 0, 0}, a1 = {0, 0, 0, 0, 0, 0, 0, 0};
  if (arow < N) {
    if (fl) {
      const u16* p = (const u16*)in + (size_t)arow * 64 + g * 8;
      a0 = *(const short8*)p;
      a1 = *(const short8*)(p + 32);
    } else {
      const float* p = (const float*)in + (size_t)arow * 64 + g * 8;
      u16 tmpv[16];
      #pragma unroll
      for (int j = 0; j < 8; j++) tmpv[j] = f2bf(p[j]);
      #pragma unroll
      for (int j = 0; j < 8; j++) tmpv[8 + j] = f2bf(p[32 + j]);
      a0 = *(short8*)tmpv;
      a1 = *(short8*)(tmpv + 8);
    }
  }
  int rbase = blockIdx.x * 64 + wid * 16 + g * 4;
  float dv[4];
  #pragma unroll
  for (int r = 0; r < 4; r++) dv[r] = (rbase + r < N) ? dinv[rbase + r] : 0.f;
  #pragma unroll
  for (int tile = 0; tile < 4; tile++) {
    short8 b0 = *(const short8*)&ws[(tile * 16 + c) * 72 + g * 8];
    short8 b1 = *(const short8*)&ws[(tile * 16 + c) * 72 + g * 8 + 32];
    f32x4 z = {0.f, 0.f, 0.f, 0.f};
    f32x4 acc = __builtin_amdgcn_mfma_f32_16x16x32_bf16(a0, b0, z, 0, 0, 0);
    acc = __builtin_amdgcn_mfma_f32_16x16x32_bf16(a1, b1, acc, 0, 0, 0);
    #pragma unroll
    for (int r = 0; r < 4; r++) {
      int orow = rbase + r;
      if (orow < N) out[(size_t)orow * 64 + tile * 16 + c] = f2bf(acc[r] * dv[r]);
    }
  }
}

// ---------------- aggregation (wave = 1 node; 8 subgroups x uint4)
// post=1 (conv1): dst = bf16( dinv_i * relu(dinv_i*sum + bias) )  [pre-scaled for conv2]
// post=0 (conv2): dst = bf16( sum )                               [W2 deferred to k_xfc]
// NOTE (R7 lesson): do NOT fuse this into MFMA-tile blocks -- the gather is
// latency-hidden by wave count (100K waves here vs 6K fused = 2x slower).
__global__ __launch_bounds__(256) void k_agg(const u16* __restrict__ src, u16* __restrict__ dst,
                                             const int* __restrict__ csr_row,
                                             const int* __restrict__ csr_ptr,
                                             const int* __restrict__ deg,
                                             const float* __restrict__ dinv,
                                             const float* __restrict__ bias, int post, int N) {
  int lane = threadIdx.x & 63;
  int wid = threadIdx.x >> 6;
  int i = blockIdx.x * 4 + wid;
  if (i >= N) return;
  int sub = lane >> 3;                 // 0..7: edge slot
  int fo  = lane & 7;                  // feature octet: feats 8*fo .. 8*fo+7
  int start = csr_ptr[i];
  int total = deg[i];
  const u16* base = src + (size_t)fo * 8;
  float a0 = 0.f, a1 = 0.f, a2 = 0.f, a3 = 0.f;
  float a4 = 0.f, a5 = 0.f, a6 = 0.f, a7 = 0.f;
  #pragma unroll 4
  for (int t = sub; t < total; t += 8) {
    int r = (t == 0) ? i : csr_row[start + t - 1];
    uint4 v = *(const uint4*)(base + (size_t)r * 64);
    a0 += __uint_as_float(v.x << 16);
    a1 += __uint_as_float(v.x & 0xffff0000u);
    a2 += __uint_as_float(v.y << 16);
    a3 += __uint_as_float(v.y & 0xffff0000u);
    a4 += __uint_as_float(v.z << 16);
    a5 += __uint_as_float(v.z & 0xffff0000u);
    a6 += __uint_as_float(v.w << 16);
    a7 += __uint_as_float(v.w & 0xffff0000u);
  }
  #pragma unroll
  for (int off = 8; off < 64; off <<= 1) {
    a0 += __shfl_xor(a0, off); a1 += __shfl_xor(a1, off);
    a2 += __shfl_xor(a2, off); a3 += __shfl_xor(a3, off);
    a4 += __shfl_xor(a4, off); a5 += __shfl_xor(a5, off);
    a6 += __shfl_xor(a6, off); a7 += __shfl_xor(a7, off);
  }
  if (sub == 0) {
    u16 o[8];
    if (post) {
      float di = dinv[i];
      float4 b0 = ((const float4*)bias)[2 * fo];
      float4 b1 = ((const float4*)bias)[2 * fo + 1];
      o[0] = f2bf(di * fmaxf(fmaf(a0, di, b0.x), 0.f));
      o[1] = f2bf(di * fmaxf(fmaf(a1, di, b0.y), 0.f));
      o[2] = f2bf(di * fmaxf(fmaf(a2, di, b0.z), 0.f));
      o[3] = f2bf(di * fmaxf(fmaf(a3, di, b0.w), 0.f));
      o[4] = f2bf(di * fmaxf(fmaf(a4, di, b1.x), 0.f));
      o[5] = f2bf(di * fmaxf(fmaf(a5, di, b1.y), 0.f));
      o[6] = f2bf(di * fmaxf(fmaf(a6, di, b1.z), 0.f));
      o[7] = f2bf(di * fmaxf(fmaf(a7, di, b1.w), 0.f));
    } else {
      o[0] = f2bf(a0); o[1] = f2bf(a1); o[2] = f2bf(a2); o[3] = f2bf(a3);
      o[4] = f2bf(a4); o[5] = f2bf(a5); o[6] = f2bf(a6); o[7] = f2bf(a7);
    }
    *(uint4*)&dst[(size_t)i * 64 + fo * 8] = *(uint4*)o;
  }
}

// -------- fused: T = relu(dinv_i*(S @ W2) + b2); fc1(relu); fc2; ssq  (MFMA)
// LDS overlay: phase A uses lds[0..4608) = W2, lds[4608..9216) = T rows
// (wave-local C->A round-trip); phase B restages lds[0..18432) = full fc1.
__global__ __launch_bounds__(256) void k_xfc(const u16* __restrict__ S,
                                             const u16* __restrict__ w2T,
                                             const u16* __restrict__ fc1T,
                                             const float* __restrict__ wf,
                                             const float* __restrict__ dinv,
                                             float* __restrict__ outf,
                                             float* __restrict__ ssum, int N) {
  __shared__ __align__(16) u16 lds[256 * 72];   // 36864 B
  __shared__ float red[16];
  u16* w2s  = lds;           // 64*72
  u16* rows = lds + 4608;    // 64*72
  int t = threadIdx.x;
  #pragma unroll
  for (int f = t; f < 512; f += 256) {
    int n = f >> 3, o = f & 7;
    *(float4*)&w2s[n * 72 + o * 8] = ((const float4*)w2T)[f];
  }
  __syncthreads();
  int lane = t & 63, wid = t >> 6;
  int g = lane >> 4, c = lane & 15;
  int arow = blockIdx.x * 64 + wid * 16 + c;
  short8 a0 = {0, 0, 0, 0, 0, 0, 0, 0}, a1 = {0, 0, 0, 0, 0, 0, 0, 0};
  if (arow < N) {
    a0 = *(const short8*)&S[(size_t)arow * 64 + g * 8];
    a1 = *(const short8*)&S[(size_t)arow * 64 + g * 8 + 32];
  }
  int rbase = blockIdx.x * 64 + wid * 16 + g * 4;
  float dv[4];
  #pragma unroll
  for (int r = 0; r < 4; r++) dv[r] = (rbase + r < N) ? dinv[rbase + r] : 0.f;
  // W2 transform -> T (bf16) into wave-local rows region
  #pragma unroll
  for (int tile = 0; tile < 4; tile++) {
    short8 b0 = *(const short8*)&w2s[(tile * 16 + c) * 72 + g * 8];
    short8 b1 = *(const short8*)&w2s[(tile * 16 + c) * 72 + g * 8 + 32];
    f32x4 z = {0.f, 0.f, 0.f, 0.f};
    f32x4 acc = __builtin_amdgcn_mfma_f32_16x16x32_bf16(a0, b0, z, 0, 0, 0);
    acc = __builtin_amdgcn_mfma_f32_16x16x32_bf16(a1, b1, acc, 0, 0, 0);
    int col = tile * 16 + c;
    float b2v = wf[64 + col];
    #pragma unroll
    for (int r = 0; r < 4; r++) {
      float tv = fmaxf(fmaf(acc[r], dv[r], b2v), 0.f);
      rows[(wid * 16 + g * 4 + r) * 72 + col] = f2bf(tv);
    }
  }
  // A-frags for fc1 from own wave's rows (wave-local; lgkmcnt handled by compiler)
  short8 t0 = *(const short8*)&rows[(wid * 16 + c) * 72 + g * 8];
  short8 t1 = *(const short8*)&rows[(wid * 16 + c) * 72 + g * 8 + 32];
  __syncthreads();   // all waves done with w2s/rows before overlay
  // stage full fc1 (256 cols x 64 k) into lds, stride 72
  #pragma unroll
  for (int f = t; f < 2048; f += 256) {
    int n = f >> 3, o = f & 7;
    *(float4*)&lds[n * 72 + o * 8] = ((const float4*)fc1T)[f];
  }
  __syncthreads();
  float psum[4] = {0.f, 0.f, 0.f, 0.f};
  #pragma unroll
  for (int tile = 0; tile < 16; tile++) {
    short8 b0 = *(const short8*)&lds[(tile * 16 + c) * 72 + g * 8];
    short8 b1 = *(const short8*)&lds[(tile * 16 + c) * 72 + g * 8 + 32];
    f32x4 z = {0.f, 0.f, 0.f, 0.f};
    f32x4 acc = __builtin_amdgcn_mfma_f32_16x16x32_bf16(t0, b0, z, 0, 0, 0);
    acc = __builtin_amdgcn_mfma_f32_16x16x32_bf16(t1, b1, acc, 0, 0, 0);
    int col = tile * 16 + c;
    float fb = wf[128 + col];
    float fw = wf[384 + col];
    #pragma unroll
    for (int r = 0; r < 4; r++) psum[r] += fmaxf(acc[r] + fb, 0.f) * fw;
  }
  #pragma unroll
  for (int off = 1; off < 16; off <<= 1) {
    #pragma unroll
    for (int r = 0; r < 4; r++) psum[r] += __shfl_xor(psum[r], off);
  }
  float fc2b = wf[640];
  if (c == 0) {
    float ss = 0.f;
    #pragma unroll
    for (int r = 0; r < 4; r++) {
      int row = rbase + r;
      if (row < N) {
        float o = psum[r] + fc2b;
        outf[row] = o;
        ss += o * o;
      }
    }
    red[wid * 4 + g] = ss;
  }
  __syncthreads();
  if (t == 0) {
    float s = 0.f;
    #pragma unroll
    for (int j = 0; j < 16; j++) s += red[j];
    atomicAdd(ssum, s);
  }
}

// ------------------------------------------------------------- L2 norm write
__global__ void k_norm(const float* __restrict__ outf, const float* __restrict__ ssum,
                       void* dout, int N, const int* flag) {
  int i = blockIdx.x * blockDim.x + threadIdx.x;
  if (i >= N) return;
  float denom = fmaxf(sqrtf(*ssum), 1e-12f);
  float v = outf[i] / denom;
  if (*flag) ((__hip_bfloat16*)dout)[i] = __float2bfloat16(v);
  else       ((float*)dout)[i] = v;
}

extern "C" void kernel_launch(void* const* d_in, const int* in_sizes, int n_in,
                              void* d_out, int out_size, void* d_ws, size_t ws_size,
                              hipStream_t stream) {
  const void* x   = d_in[0];
  const int* eidx = (const int*)d_in[1];
  const void* W1  = d_in[2]; const void* b1  = d_in[3];
  const void* W2  = d_in[4]; const void* b2  = d_in[5];
  const void* f1w = d_in[6]; const void* f1b = d_in[7];
  const void* f2w = d_in[8]; const void* f2b = d_in[9];
  int N = in_sizes[0] / 64;
  int E = in_sizes[1] / 2;
  int NB = (N + 255) >> 8;           // 256-node buckets
  int GEB = (E + 8191) / 8192;

  char* ws = (char*)d_ws;
  size_t off = 0;
  auto alloc = [&](size_t b) {
    void* p = ws + off;
    off = (off + b + 255) & ~(size_t)255;
    return p;
  };
  int*   flag  = (int*)  alloc(4);
  float* ssum  = (float*)alloc(4);
  int*   bcnt  = (int*)  alloc(512 * 4);
  int*   bbase = (int*)  alloc(512 * 4);
  int*   bcur  = (int*)  alloc(512 * 4);
  int*   bhist = (int*)  alloc((size_t)GEB * 512 * 4);
  u32*   bdata = (u32*)  alloc((size_t)E * 4);
  int*   deg   = (int*)  alloc((size_t)N * 4);
  int*   ptr   = (int*)  alloc((size_t)N * 4);
  float* dinv  = (float*)alloc((size_t)N * 4);
  int*   crow  = (int*)  alloc((size_t)E * 4);
  u16*   wbh   = (u16*)  alloc(24576 * 2);
  float* wbf   = (float*)alloc(641 * 4);
  u16*   HA    = (u16*)  alloc((size_t)N * 64 * 2);
  u16*   HT    = (u16*)  alloc((size_t)N * 64 * 2);
  float* outf  = (float*)alloc((size_t)N * 4);

  int GN = (N + 255) / 256;
  int NT = (N + 63) / 64;

  hipMemsetAsync(bcnt, 0, 512 * 4, stream);
  hipMemsetAsync(ssum, 0, 4, stream);
  k_conv_w<<<(24576 + 641 + 255) / 256, 256, 0, stream>>>(x, W1, b1, W2, b2, f1w, f1b, f2w, f2b,
                                                          wbh, wbf, flag);
  // CSR build (bucketed, 256-node buckets)
  k_bcount<<<GEB, 256, 0, stream>>>(eidx, E, bcnt, bhist);
  k_bscan<<<1, 512, 0, stream>>>(bcnt, bbase, bcur);
  k_bfill<<<GEB, 256, 0, stream>>>(eidx, E, bhist, bcur, bdata);
  k_csr<<<NB, 256, 0, stream>>>(bdata, bbase, bcnt, deg, dinv, ptr, crow, N);

  // conv1 transform (reads raw x, converts inline): HT = dinv*(x@W1)
  k_xform<<<NT, 256, 0, stream>>>(x, 0, flag, wbh + 0, dinv, HT, N);
  // conv1 aggregate: HA = dinv * relu(dinv*sum + b1)   (pre-scaled for conv2)
  k_agg<<<(N + 3) / 4, 256, 0, stream>>>(HT, HA, crow, ptr, deg, dinv, wbf + 0, 1, N);
  // conv2 aggregate (pure sum, W2 deferred): HT = sum of HA rows
  k_agg<<<(N + 3) / 4, 256, 0, stream>>>(HA, HT, crow, ptr, deg, dinv, wbf, 0, N);
  // fused W2-transform + MLP + sum of squares
  k_xfc<<<NT, 256, 0, stream>>>(HT, wbh + 4096, wbh + 8192, wbf, dinv, outf, ssum, N);
  // normalize + write
  k_norm<<<GN, 256, 0, stream>>>(outf, ssum, d_out, N, flag);
}

// Round 12
// 274.191 us; speedup vs baseline: 1.1347x; 1.0036x over previous
//
#include <hip/hip_runtime.h>
#include <hip/hip_bf16.h>

typedef unsigned short u16;
typedef unsigned int u32;
typedef __attribute__((ext_vector_type(8))) short short8;
typedef __attribute__((ext_vector_type(4))) float f32x4;

__device__ __forceinline__ float bf2f(u16 h) {
  return __uint_as_float(((u32)h) << 16);
}
__device__ __forceinline__ float ldconv(const void* p, int i, int fl) {
  return fl ? bf2f(((const u16*)p)[i]) : ((const float*)p)[i];
}
__device__ __forceinline__ u16 f2bf(float v) {
  __hip_bfloat16 h = __float2bfloat16(v);
  return *(u16*)&h;
}

// ------------------- weight conversion + dtype sniff + counter zeroing
// wbh (u16): W1T [0,4096) W2T [4096,8192) fc1T [8192,24576)   (all [n][k], k=64)
// wbf (f32): b1[0,64) b2[64,128) fc1b[128,384) fc2w[384,640) fc2b[640]
__global__ __launch_bounds__(256) void k_conv_w(const void* x,
                         const void* W1, const void* b1, const void* W2, const void* b2,
                         const void* f1w, const void* f1b, const void* f2w, const void* f2b,
                         u16* wbh, float* wbf, int* flag, float* ssum,
                         int* bcnt, int* bcur) {
  __shared__ float red[256];
  int t = threadIdx.x;
  // each block sniffs dtype independently (reads 2 KB of x, L2-resident)
  const u16* hx = (const u16*)x;
  float m = 0.f;
  for (int i = t; i < 1024; i += 256) m = fmaxf(m, fabsf(bf2f(hx[i])));
  red[t] = m; __syncthreads();
  for (int off = 128; off > 0; off >>= 1) {
    if (t < off) red[t] = fmaxf(red[t], red[t + off]);
    __syncthreads();
  }
  int fl = (red[0] < 1000.0f) ? 1 : 0;
  if (blockIdx.x == 0) {
    bcnt[t] = 0; bcnt[t + 256] = 0;
    bcur[t] = 0; bcur[t + 256] = 0;
    if (t == 0) { *flag = fl; *ssum = 0.f; }
  }
  int i = blockIdx.x * 256 + t;
  if (i < 4096) {
    int n = i >> 6, k = i & 63;
    wbh[i] = f2bf(ldconv(W1, k * 64 + n, fl));
  } else if (i < 8192) {
    int j = i - 4096; int n = j >> 6, k = j & 63;
    wbh[i] = f2bf(ldconv(W2, k * 64 + n, fl));
  } else if (i < 24576) {
    int j = i - 8192; int n = j >> 6, k = j & 63;
    wbh[i] = f2bf(ldconv(f1w, k * 256 + n, fl));
  } else if (i < 24576 + 641) {
    int j = i - 24576;
    float v;
    if (j < 64)       v = ldconv(b1,  j,       fl);
    else if (j < 128) v = ldconv(b2,  j - 64,  fl);
    else if (j < 384) v = ldconv(f1b, j - 128, fl);
    else if (j < 640) v = ldconv(f2w, j - 384, fl);
    else              v = ldconv(f2b, 0,       fl);
    wbf[j] = v;
  }
}

// --------------------------------------- bucketed CSR build (256-node buckets)
// QUARANTINE NOTE (R8): this scan-based two-pass build is the verified one.
// The single-pass fixed-capacity variant intermittently corrupted results.
// R12 change: the global 512-scan is computed per-block in LDS (k_bscan
// deleted); reservation arithmetic is identical (zeroed cursor + local base).
__global__ __launch_bounds__(256) void k_bcount(const int* __restrict__ eidx, int E,
                                                int* bcnt, int* blockhist) {
  __shared__ int hist[512];
  int t = threadIdx.x;
  hist[t] = 0; hist[t + 256] = 0;
  __syncthreads();
  int e0 = blockIdx.x * 8192;
  int e1 = min(e0 + 8192, E);
  for (int e = e0 + t; e < e1; e += 256) atomicAdd(&hist[eidx[E + e] >> 8], 1);
  __syncthreads();
  int* bh = blockhist + blockIdx.x * 512;
  for (int j = t; j < 512; j += 256) {
    bh[j] = hist[j];
    if (hist[j]) atomicAdd(&bcnt[j], hist[j]);
  }
}

__global__ __launch_bounds__(256) void k_bfill(const int* __restrict__ eidx, int E,
                                               const int* __restrict__ bcnt,
                                               const int* __restrict__ blockhist,
                                               int* bcur, u32* bdata) {
  __shared__ int base[512];
  __shared__ int hist[512];
  __shared__ int scan[512];
  int t = threadIdx.x;
  // per-block inclusive 512-scan of bcnt (Hillis-Steele, 2 elems/thread)
  scan[t] = bcnt[t]; scan[t + 256] = bcnt[t + 256];
  __syncthreads();
  for (int off = 1; off < 512; off <<= 1) {
    int u0 = (t >= off) ? scan[t - off] : 0;
    int u1 = ((t + 256) >= off) ? scan[t + 256 - off] : 0;
    __syncthreads();
    scan[t] += u0; scan[t + 256] += u1;
    __syncthreads();
  }
  const int* bh = blockhist + blockIdx.x * 512;
  for (int j = t; j < 512; j += 256) {
    int c = bh[j];
    int gb = scan[j] - bcnt[j];          // exclusive global base of bucket j
    base[j] = c ? gb + atomicAdd(&bcur[j], c) : 0;
    hist[j] = 0;
  }
  __syncthreads();
  int e0 = blockIdx.x * 8192;
  int e1 = min(e0 + 8192, E);
  for (int e = e0 + t; e < e1; e += 256) {
    int src = eidx[e];
    int tgt = eidx[E + e];
    int b = tgt >> 8;
    int idx = atomicAdd(&hist[b], 1);
    bdata[base[b] + idx] = ((u32)src << 8) | (u32)(tgt & 255);
  }
}

// One block per bucket: histogram -> deg/dinv/ptr, LDS scan, LDS scatter, seq write.
__global__ __launch_bounds__(256) void k_csr(const u32* __restrict__ bdata,
                                             const int* __restrict__ bcnt,
                                             int* __restrict__ deg, float* __restrict__ dinv,
                                             int* __restrict__ ptr, int* __restrict__ crow,
                                             int N) {
  __shared__ int lds[8192];
  __shared__ int hist[256];
  __shared__ int tmp[256];
  __shared__ int cur[256];
  int b = blockIdx.x, t = threadIdx.x;
  // per-block scan of bcnt to get this bucket's global base (reuses lds)
  lds[t] = bcnt[t]; lds[t + 256] = bcnt[t + 256];
  __syncthreads();
  for (int off = 1; off < 512; off <<= 1) {
    int u0 = (t >= off) ? lds[t - off] : 0;
    int u1 = ((t + 256) >= off) ? lds[t + 256 - off] : 0;
    __syncthreads();
    lds[t] += u0; lds[t + 256] += u1;
    __syncthreads();
  }
  int base = lds[b] - bcnt[b];           // exclusive
  int cnt = bcnt[b];
  __syncthreads();                       // done with lds-as-scan
  int node0 = b << 8;
  int ncnt = min(256, N - node0);
  hist[t] = 0;
  __syncthreads();
  for (int e = t; e < cnt; e += 256) atomicAdd(&hist[bdata[base + e] & 255], 1);
  __syncthreads();
  int h = hist[t];
  if (t < ncnt) {
    deg[node0 + t] = h + 1;
    dinv[node0 + t] = 1.0f / sqrtf((float)(h + 1));
  }
  tmp[t] = h; __syncthreads();
  for (int off = 1; off < 256; off <<= 1) {
    int u = (t >= off) ? tmp[t - off] : 0;
    __syncthreads();
    tmp[t] += u;
    __syncthreads();
  }
  int excl = tmp[t] - h;
  if (t < ncnt) ptr[node0 + t] = base + excl;
  cur[t] = excl;
  __syncthreads();
  for (int e = t; e < cnt; e += 256) {
    u32 pk = bdata[base + e];
    int pos = atomicAdd(&cur[pk & 255], 1);
    if (pos < 8192) lds[pos] = (int)(pk >> 8);
  }
  __syncthreads();
  for (int j = t; j < cnt; j += 256) crow[base + j] = lds[j];
}

// ---------------- transform: out[r,:] = dinv[r] * (in[r,:] @ W)  (MFMA, bf16)
__global__ __launch_bounds__(256) void k_xform(const void* __restrict__ in, int inbf,
                                               const int* __restrict__ flagp,
                                               const u16* __restrict__ wT,
                                               const float* __restrict__ dinv,
                                               u16* __restrict__ out, int N) {
  __shared__ __align__(16) u16 ws[64 * 72];
  int t = threadIdx.x;
  #pragma unroll
  for (int f = t; f < 512; f += 256) {
    int n = f >> 3, o = f & 7;
    *(float4*)&ws[n * 72 + o * 8] = ((const float4*)wT)[f];
  }
  __syncthreads();
  int fl = inbf ? 1 : *flagp;
  int lane = t & 63, wid = t >> 6;
  int g = lane >> 4, c = lane & 15;
  int arow = blockIdx.x * 64 + wid * 16 + c;
  short8 a0 = {0, 0, 0, 0, 0, 0, 0, 0}, a1 = {0, 0, 0, 0, 0, 0, 0, 0};
  if (arow < N) {
    if (fl) {
      const u16* p = (const u16*)in + (size_t)arow * 64 + g * 8;
      a0 = *(const short8*)p;
      a1 = *(const short8*)(p + 32);
    } else {
      const float* p = (const float*)in + (size_t)arow * 64 + g * 8;
      u16 tmpv[16];
      #pragma unroll
      for (int j = 0; j < 8; j++) tmpv[j] = f2bf(p[j]);
      #pragma unroll
      for (int j = 0; j < 8; j++) tmpv[8 + j] = f2bf(p[32 + j]);
      a0 = *(short8*)tmpv;
      a1 = *(short8*)(tmpv + 8);
    }
  }
  int rbase = blockIdx.x * 64 + wid * 16 + g * 4;
  float dv[4];
  #pragma unroll
  for (int r = 0; r < 4; r++) dv[r] = (rbase + r < N) ? dinv[rbase + r] : 0.f;
  #pragma unroll
  for (int tile = 0; tile < 4; tile++) {
    short8 b0 = *(const short8*)&ws[(tile * 16 + c) * 72 + g * 8];
    short8 b1 = *(const short8*)&ws[(tile * 16 + c) * 72 + g * 8 + 32];
    f32x4 z = {0.f, 0.f, 0.f, 0.f};
    f32x4 acc = __builtin_amdgcn_mfma_f32_16x16x32_bf16(a0, b0, z, 0, 0, 0);
    acc = __builtin_amdgcn_mfma_f32_16x16x32_bf16(a1, b1, acc, 0, 0, 0);
    #pragma unroll
    for (int r = 0; r < 4; r++) {
      int orow = rbase + r;
      if (orow < N) out[(size_t)orow * 64 + tile * 16 + c] = f2bf(acc[r] * dv[r]);
    }
  }
}

// ---------------- aggregation (wave = 1 node; 8 subgroups x uint4)
// post=1 (conv1): dst = bf16( dinv_i * relu(dinv_i*sum + bias) )  [pre-scaled for conv2]
// post=0 (conv2): dst = bf16( sum )                               [W2 deferred to k_xfc]
// NOTE (R7 lesson): do NOT fuse this into MFMA-tile blocks -- the gather is
// latency-hidden by wave count (100K waves here vs 6K fused = 2x slower).
__global__ __launch_bounds__(256) void k_agg(const u16* __restrict__ src, u16* __restrict__ dst,
                                             const int* __restrict__ csr_row,
                                             const int* __restrict__ csr_ptr,
                                             const int* __restrict__ deg,
                                             const float* __restrict__ dinv,
                                             const float* __restrict__ bias, int post, int N) {
  int lane = threadIdx.x & 63;
  int wid = threadIdx.x >> 6;
  int i = blockIdx.x * 4 + wid;
  if (i >= N) return;
  int sub = lane >> 3;                 // 0..7: edge slot
  int fo  = lane & 7;                  // feature octet: feats 8*fo .. 8*fo+7
  int start = csr_ptr[i];
  int total = deg[i];
  const u16* base = src + (size_t)fo * 8;
  float a0 = 0.f, a1 = 0.f, a2 = 0.f, a3 = 0.f;
  float a4 = 0.f, a5 = 0.f, a6 = 0.f, a7 = 0.f;
  #pragma unroll 4
  for (int t = sub; t < total; t += 8) {
    int r = (t == 0) ? i : csr_row[start + t - 1];
    uint4 v = *(const uint4*)(base + (size_t)r * 64);
    a0 += __uint_as_float(v.x << 16);
    a1 += __uint_as_float(v.x & 0xffff0000u);
    a2 += __uint_as_float(v.y << 16);
    a3 += __uint_as_float(v.y & 0xffff0000u);
    a4 += __uint_as_float(v.z << 16);
    a5 += __uint_as_float(v.z & 0xffff0000u);
    a6 += __uint_as_float(v.w << 16);
    a7 += __uint_as_float(v.w & 0xffff0000u);
  }
  #pragma unroll
  for (int off = 8; off < 64; off <<= 1) {
    a0 += __shfl_xor(a0, off); a1 += __shfl_xor(a1, off);
    a2 += __shfl_xor(a2, off); a3 += __shfl_xor(a3, off);
    a4 += __shfl_xor(a4, off); a5 += __shfl_xor(a5, off);
    a6 += __shfl_xor(a6, off); a7 += __shfl_xor(a7, off);
  }
  if (sub == 0) {
    u16 o[8];
    if (post) {
      float di = dinv[i];
      float4 b0 = ((const float4*)bias)[2 * fo];
      float4 b1 = ((const float4*)bias)[2 * fo + 1];
      o[0] = f2bf(di * fmaxf(fmaf(a0, di, b0.x), 0.f));
      o[1] = f2bf(di * fmaxf(fmaf(a1, di, b0.y), 0.f));
      o[2] = f2bf(di * fmaxf(fmaf(a2, di, b0.z), 0.f));
      o[3] = f2bf(di * fmaxf(fmaf(a3, di, b0.w), 0.f));
      o[4] = f2bf(di * fmaxf(fmaf(a4, di, b1.x), 0.f));
      o[5] = f2bf(di * fmaxf(fmaf(a5, di, b1.y), 0.f));
      o[6] = f2bf(di * fmaxf(fmaf(a6, di, b1.z), 0.f));
      o[7] = f2bf(di * fmaxf(fmaf(a7, di, b1.w), 0.f));
    } else {
      o[0] = f2bf(a0); o[1] = f2bf(a1); o[2] = f2bf(a2); o[3] = f2bf(a3);
      o[4] = f2bf(a4); o[5] = f2bf(a5); o[6] = f2bf(a6); o[7] = f2bf(a7);
    }
    *(uint4*)&dst[(size_t)i * 64 + fo * 8] = *(uint4*)o;
  }
}

// -------- fused: T = relu(dinv_i*(S @ W2) + b2); fc1(relu); fc2; ssq  (MFMA)
// LDS overlay: phase A uses lds[0..4608) = W2, lds[4608..9216) = T rows
// (wave-local C->A round-trip); phase B restages lds[0..18432) = full fc1.
__global__ __launch_bounds__(256) void k_xfc(const u16* __restrict__ S,
                                             const u16* __restrict__ w2T,
                                             const u16* __restrict__ fc1T,
                                             const float* __restrict__ wf,
                                             const float* __restrict__ dinv,
                                             float* __restrict__ outf,
                                             float* __restrict__ ssum, int N) {
  __shared__ __align__(16) u16 lds[256 * 72];   // 36864 B
  __shared__ float red[16];
  u16* w2s  = lds;           // 64*72
  u16* rows = lds + 4608;    // 64*72
  int t = threadIdx.x;
  #pragma unroll
  for (int f = t; f < 512; f += 256) {
    int n = f >> 3, o = f & 7;
    *(float4*)&w2s[n * 72 + o * 8] = ((const float4*)w2T)[f];
  }
  __syncthreads();
  int lane = t & 63, wid = t >> 6;
  int g = lane >> 4, c = lane & 15;
  int arow = blockIdx.x * 64 + wid * 16 + c;
  short8 a0 = {0, 0, 0, 0, 0, 0, 0, 0}, a1 = {0, 0, 0, 0, 0, 0, 0, 0};
  if (arow < N) {
    a0 = *(const short8*)&S[(size_t)arow * 64 + g * 8];
    a1 = *(const short8*)&S[(size_t)arow * 64 + g * 8 + 32];
  }
  int rbase = blockIdx.x * 64 + wid * 16 + g * 4;
  float dv[4];
  #pragma unroll
  for (int r = 0; r < 4; r++) dv[r] = (rbase + r < N) ? dinv[rbase + r] : 0.f;
  // W2 transform -> T (bf16) into wave-local rows region
  #pragma unroll
  for (int tile = 0; tile < 4; tile++) {
    short8 b0 = *(const short8*)&w2s[(tile * 16 + c) * 72 + g * 8];
    short8 b1 = *(const short8*)&w2s[(tile * 16 + c) * 72 + g * 8 + 32];
    f32x4 z = {0.f, 0.f, 0.f, 0.f};
    f32x4 acc = __builtin_amdgcn_mfma_f32_16x16x32_bf16(a0, b0, z, 0, 0, 0);
    acc = __builtin_amdgcn_mfma_f32_16x16x32_bf16(a1, b1, acc, 0, 0, 0);
    int col = tile * 16 + c;
    float b2v = wf[64 + col];
    #pragma unroll
    for (int r = 0; r < 4; r++) {
      float tv = fmaxf(fmaf(acc[r], dv[r], b2v), 0.f);
      rows[(wid * 16 + g * 4 + r) * 72 + col] = f2bf(tv);
    }
  }
  // A-frags for fc1 from own wave's rows (wave-local; lgkmcnt handled by compiler)
  short8 t0 = *(const short8*)&rows[(wid * 16 + c) * 72 + g * 8];
  short8 t1 = *(const short8*)&rows[(wid * 16 + c) * 72 + g * 8 + 32];
  __syncthreads();   // all waves done with w2s/rows before overlay
  // stage full fc1 (256 cols x 64 k) into lds, stride 72
  #pragma unroll
  for (int f = t; f < 2048; f += 256) {
    int n = f >> 3, o = f & 7;
    *(float4*)&lds[n * 72 + o * 8] = ((const float4*)fc1T)[f];
  }
  __syncthreads();
  float psum[4] = {0.f, 0.f, 0.f, 0.f};
  #pragma unroll
  for (int tile = 0; tile < 16; tile++) {
    short8 b0 = *(const short8*)&lds[(tile * 16 + c) * 72 + g * 8];
    short8 b1 = *(const short8*)&lds[(tile * 16 + c) * 72 + g * 8 + 32];
    f32x4 z = {0.f, 0.f, 0.f, 0.f};
    f32x4 acc = __builtin_amdgcn_mfma_f32_16x16x32_bf16(t0, b0, z, 0, 0, 0);
    acc = __builtin_amdgcn_mfma_f32_16x16x32_bf16(t1, b1, acc, 0, 0, 0);
    int col = tile * 16 + c;
    float fb = wf[128 + col];
    float fw = wf[384 + col];
    #pragma unroll
    for (int r = 0; r < 4; r++) psum[r] += fmaxf(acc[r] + fb, 0.f) * fw;
  }
  #pragma unroll
  for (int off = 1; off < 16; off <<= 1) {
    #pragma unroll
    for (int r = 0; r < 4; r++) psum[r] += __shfl_xor(psum[r], off);
  }
  float fc2b = wf[640];
  if (c == 0) {
    float ss = 0.f;
    #pragma unroll
    for (int r = 0; r < 4; r++) {
      int row = rbase + r;
      if (row < N) {
        float o = psum[r] + fc2b;
        outf[row] = o;
        ss += o * o;
      }
    }
    red[wid * 4 + g] = ss;
  }
  __syncthreads();
  if (t == 0) {
    float s = 0.f;
    #pragma unroll
    for (int j = 0; j < 16; j++) s += red[j];
    atomicAdd(ssum, s);
  }
}

// ------------------------------------------------------------- L2 norm write
__global__ void k_norm(const float* __restrict__ outf, const float* __restrict__ ssum,
                       void* dout, int N, const int* flag) {
  int i = blockIdx.x * blockDim.x + threadIdx.x;
  if (i >= N) return;
  float denom = fmaxf(sqrtf(*ssum), 1e-12f);
  float v = outf[i] / denom;
  if (*flag) ((__hip_bfloat16*)dout)[i] = __float2bfloat16(v);
  else       ((float*)dout)[i] = v;
}

extern "C" void kernel_launch(void* const* d_in, const int* in_sizes, int n_in,
                              void* d_out, int out_size, void* d_ws, size_t ws_size,
                              hipStream_t stream) {
  const void* x   = d_in[0];
  const int* eidx = (const int*)d_in[1];
  const void* W1  = d_in[2]; const void* b1  = d_in[3];
  const void* W2  = d_in[4]; const void* b2  = d_in[5];
  const void* f1w = d_in[6]; const void* f1b = d_in[7];
  const void* f2w = d_in[8]; const void* f2b = d_in[9];
  int N = in_sizes[0] / 64;
  int E = in_sizes[1] / 2;
  int NB = (N + 255) >> 8;           // 256-node buckets
  int GEB = (E + 8191) / 8192;

  char* ws = (char*)d_ws;
  size_t off = 0;
  auto alloc = [&](size_t b) {
    void* p = ws + off;
    off = (off + b + 255) & ~(size_t)255;
    return p;
  };
  int*   flag  = (int*)  alloc(4);
  float* ssum  = (float*)alloc(4);
  int*   bcnt  = (int*)  alloc(512 * 4);
  int*   bcur  = (int*)  alloc(512 * 4);
  int*   bhist = (int*)  alloc((size_t)GEB * 512 * 4);
  u32*   bdata = (u32*)  alloc((size_t)E * 4);
  int*   deg   = (int*)  alloc((size_t)N * 4);
  int*   ptr   = (int*)  alloc((size_t)N * 4);
  float* dinv  = (float*)alloc((size_t)N * 4);
  int*   crow  = (int*)  alloc((size_t)E * 4);
  u16*   wbh   = (u16*)  alloc(24576 * 2);
  float* wbf   = (float*)alloc(641 * 4);
  u16*   HA    = (u16*)  alloc((size_t)N * 64 * 2);
  u16*   HT    = (u16*)  alloc((size_t)N * 64 * 2);
  float* outf  = (float*)alloc((size_t)N * 4);

  int GN = (N + 255) / 256;
  int NT = (N + 63) / 64;

  // weights + dtype sniff + zero bcnt/bcur/ssum
  k_conv_w<<<(24576 + 641 + 255) / 256, 256, 0, stream>>>(x, W1, b1, W2, b2, f1w, f1b, f2w, f2b,
                                                          wbh, wbf, flag, ssum, bcnt, bcur);
  // CSR build (bucketed, 256-node buckets; scan computed per-block in LDS)
  k_bcount<<<GEB, 256, 0, stream>>>(eidx, E, bcnt, bhist);
  k_bfill<<<GEB, 256, 0, stream>>>(eidx, E, bcnt, bhist, bcur, bdata);
  k_csr<<<NB, 256, 0, stream>>>(bdata, bcnt, deg, dinv, ptr, crow, N);

  // conv1 transform (reads raw x, converts inline): HT = dinv*(x@W1)
  k_xform<<<NT, 256, 0, stream>>>(x, 0, flag, wbh + 0, dinv, HT, N);
  // conv1 aggregate: HA = dinv * relu(dinv*sum + b1)   (pre-scaled for conv2)
  k_agg<<<(N + 3) / 4, 256, 0, stream>>>(HT, HA, crow, ptr, deg, dinv, wbf + 0, 1, N);
  // conv2 aggregate (pure sum, W2 deferred): HT = sum of HA rows
  k_agg<<<(N + 3) / 4, 256, 0, stream>>>(HA, HT, crow, ptr, deg, dinv, wbf, 0, N);
  // fused W2-transform + MLP + sum of squares
  k_xfc<<<NT, 256, 0, stream>>>(HT, wbh + 4096, wbh + 8192, wbf, dinv, outf, ssum, N);
  // normalize + write
  k_norm<<<GN, 256, 0, stream>>>(outf, ssum, d_out, N, flag);
}